// Round 2
// baseline (157762.280 us; speedup 1.0000x reference)
//
#include <hip/hip_runtime.h>
#include <stdint.h>

#define BB 16
#define TT 1000
#define SZ 896
#define HF 448
#define NCWG 224
#define NSWG 16
#define NWG  240

// Persistent device-global state (avoids any ws_size assumptions).
__device__ float g_wbct[HF * 256];       // W_bc transposed [448][256]
__device__ float g_wbft[HF * 256];       // W_bf transposed [448][256]
__device__ float g_hid[2 * BB * SZ];     // double-buffered hidden [2][16][896]
__device__ float g_hpf[3 * HF * BB];     // fine-gate hp rows [3][448][16]
__device__ float g_cv[BB];
__device__ float g_fv[BB];
__device__ __align__(128) uint32_t g_f1; // compute->sampler counter
__device__ __align__(128) uint32_t g_f2; // sampler->compute counter

__device__ __forceinline__ uint32_t rotl32(uint32_t v, int d) {
  return (v << d) | (v >> (32 - d));
}

// JAX threefry2x32 block (20 rounds), bit-exact
__device__ __forceinline__ uint2 tf2(uint32_t k0, uint32_t k1, uint32_t x0, uint32_t x1) {
  const uint32_t k2 = k0 ^ k1 ^ 0x1BD11BDAu;
  x0 += k0; x1 += k1;
  x0 += x1; x1 = rotl32(x1,13); x1 ^= x0;
  x0 += x1; x1 = rotl32(x1,15); x1 ^= x0;
  x0 += x1; x1 = rotl32(x1,26); x1 ^= x0;
  x0 += x1; x1 = rotl32(x1, 6); x1 ^= x0;
  x0 += k1; x1 += k2 + 1u;
  x0 += x1; x1 = rotl32(x1,17); x1 ^= x0;
  x0 += x1; x1 = rotl32(x1,29); x1 ^= x0;
  x0 += x1; x1 = rotl32(x1,16); x1 ^= x0;
  x0 += x1; x1 = rotl32(x1,24); x1 ^= x0;
  x0 += k2; x1 += k0 + 2u;
  x0 += x1; x1 = rotl32(x1,13); x1 ^= x0;
  x0 += x1; x1 = rotl32(x1,15); x1 ^= x0;
  x0 += x1; x1 = rotl32(x1,26); x1 ^= x0;
  x0 += x1; x1 = rotl32(x1, 6); x1 ^= x0;
  x0 += k0; x1 += k1 + 3u;
  x0 += x1; x1 = rotl32(x1,17); x1 ^= x0;
  x0 += x1; x1 = rotl32(x1,29); x1 ^= x0;
  x0 += x1; x1 = rotl32(x1,16); x1 ^= x0;
  x0 += x1; x1 = rotl32(x1,24); x1 ^= x0;
  x0 += k1; x1 += k2 + 4u;
  x0 += x1; x1 = rotl32(x1,13); x1 ^= x0;
  x0 += x1; x1 = rotl32(x1,15); x1 ^= x0;
  x0 += x1; x1 = rotl32(x1,26); x1 ^= x0;
  x0 += x1; x1 = rotl32(x1, 6); x1 ^= x0;
  x0 += k2; x1 += k0 + 5u;
  return make_uint2(x0, x1);
}

// JAX gumbel from raw 32 bits: u = max(tiny, ((bits>>9)|0x3f800000)-1 + tiny); -log(-log(u))
__device__ __forceinline__ float gumbel_bits(uint32_t bits) {
  const float tiny = 1.17549435e-38f;
  float f = __uint_as_float((bits >> 9) | 0x3f800000u) - 1.0f;
  float u = fmaxf(tiny, f + tiny);
  return -logf(-logf(u));
}

// 256-bin logits: llds[n] = dot(vec[0:448], WT[:,n]) + bias[n]; WT is [448][256]
__device__ __forceinline__ void logits256(const float* __restrict__ WT,
                                          const float* __restrict__ bias,
                                          const float* __restrict__ vec,
                                          float* __restrict__ llds, int tid) {
  const int n4 = tid >> 2, q = tid & 3;
  float ax = 0.f, ay = 0.f, az = 0.f, aw = 0.f;
  const float* wp = WT + (size_t)(q * 112) * 256 + 4 * n4;
  const float* cp = vec + q * 112;
#pragma unroll 8
  for (int ii = 0; ii < 112; ++ii) {
    const float c = cp[ii];
    const float4 w4 = *(const float4*)(wp + (size_t)ii * 256);
    ax = fmaf(c, w4.x, ax); ay = fmaf(c, w4.y, ay);
    az = fmaf(c, w4.z, az); aw = fmaf(c, w4.w, aw);
  }
  ax += __shfl_xor(ax, 1); ax += __shfl_xor(ax, 2);
  ay += __shfl_xor(ay, 1); ay += __shfl_xor(ay, 2);
  az += __shfl_xor(az, 1); az += __shfl_xor(az, 2);
  aw += __shfl_xor(aw, 1); aw += __shfl_xor(aw, 2);
  if (q == 0) {
    llds[4 * n4 + 0] = ax + bias[4 * n4 + 0];
    llds[4 * n4 + 1] = ay + bias[4 * n4 + 1];
    llds[4 * n4 + 2] = az + bias[4 * n4 + 2];
    llds[4 * n4 + 3] = aw + bias[4 * n4 + 3];
  }
}

// categorical, partitionable threefry: counter = (hi=0, lo=b*256+n), bits = x0^x1.
// argmax(logits + gumbel), first-max tiebreak; all threads return same value
__device__ __forceinline__ int sample256(const float* __restrict__ llds,
                                         uint32_t k0, uint32_t k1, int b, int tid,
                                         float* __restrict__ redS, int* __restrict__ redI) {
  const uint2 o = tf2(k0, k1, 0u, (uint32_t)(b * 256 + tid));
  const uint32_t bits = o.x ^ o.y;
  float s = llds[tid] + gumbel_bits(bits);
  int idx = tid;
#pragma unroll
  for (int mask = 1; mask < 64; mask <<= 1) {
    const float so = __shfl_xor(s, mask);
    const int   io = __shfl_xor(idx, mask);
    if (so > s || (so == s && io < idx)) { s = so; idx = io; }
  }
  if ((tid & 63) == 0) { redS[tid >> 6] = s; redI[tid >> 6] = idx; }
  __syncthreads();
  float bs = redS[0]; int bi = redI[0];
#pragma unroll
  for (int w = 1; w < 4; ++w) {
    const float so = redS[w]; const int io = redI[w];
    if (so > bs || (so == bs && io < bi)) { bs = so; bi = io; }
  }
  return bi;
}

__global__ __launch_bounds__(256, 1) void wavernn_init(const float* __restrict__ W_bc,
                                                       const float* __restrict__ W_bf) {
  const int idx = blockIdx.x * 256 + threadIdx.x;   // grid 448*256 = 114688
  const int ich = idx >> 8, n = idx & 255;
  g_wbct[idx] = W_bc[n * HF + ich];
  g_wbft[idx] = W_bf[n * HF + ich];
  if (idx < 2 * BB * SZ) g_hid[idx] = 0.f;
  if (idx < BB) { g_cv[idx] = -1.f; g_fv[idx] = -1.f; }
  if (idx == 0) { g_f1 = 0u; g_f2 = 0u; }
}

__global__ __launch_bounds__(256, 1) void wavernn_main(
    const float* __restrict__ cond, const float* __restrict__ gib,
    const float* __restrict__ W_h,  const float* __restrict__ b_h,
    const float* __restrict__ W_ci, const float* __restrict__ b_ci,
    const float* __restrict__ W_fi, const float* __restrict__ b_fi,
    const float* __restrict__ b_bc, const float* __restrict__ b_bf,
    float* __restrict__ out) {
  __shared__ float hlds[14400];   // compute: [16][900] padded hidden; sampler: aliased scratch
  float* hidbuf = g_hid;
  uint32_t* F1 = &g_f1;
  uint32_t* F2 = &g_f2;
  const int wg = blockIdx.x, tid = threadIdx.x;

  if (wg < NCWG) {
    // ================= compute role: hp matvec + coarse gates + fine hp publish ==========
    const int wave = tid >> 6, lane = tid & 63;
    const int l32 = lane >> 1, b2 = lane & 1;
    const bool isC = wave < 2;
    const int chan = (wg << 1) | (wave & 1);           // 0..447
    const int rb = isC ? chan : (HF + chan);
    float4 w[3][7];                                     // W_h rows in registers, permanent
    float brow[3];
#pragma unroll
    for (int r = 0; r < 3; ++r) {
      const int row = r * SZ + rb;
      brow[r] = b_h[row];
#pragma unroll
      for (int m = 0; m < 7; ++m)
        w[r][m] = *(const float4*)&W_h[(size_t)row * SZ + 4 * l32 + 128 * m];
    }
    float wci0[3], wci1[3], bcie[3];
    if (isC) {
#pragma unroll
      for (int g = 0; g < 3; ++g) {
        const int rr = g * HF + chan;
        wci0[g] = W_ci[2 * rr]; wci1[g] = W_ci[2 * rr + 1];
        bcie[g] = b_ci[rr] + gib[g * SZ + chan];
      }
    }
    for (int t = 0; t < TT; ++t) {
      const int cur = t & 1, nxt = cur ^ 1;
      if (t > 0 && tid == 0) {
        while (__hip_atomic_load(F2, __ATOMIC_ACQUIRE, __HIP_MEMORY_SCOPE_AGENT)
               < (uint32_t)(NSWG * t)) {}
      }
      __syncthreads();
      { // stage hidden[cur] -> LDS (stride 900 to avoid bank conflicts)
        const int sb = tid >> 4, sl = tid & 15;
        const float* src = hidbuf + (size_t)cur * BB * SZ + sb * SZ + 56 * sl;
        float* dst = hlds + sb * 900 + 56 * sl;
#pragma unroll
        for (int m = 0; m < 14; ++m)
          *(float4*)(dst + 4 * m) = *(const float4*)(src + 4 * m);
      }
      float cndv0 = 0.f, cndv1 = 0.f, cndv2 = 0.f, cvv = 0.f, fvv = 0.f;
      if (isC && lane < 16) {
        const size_t base = (((size_t)lane * TT + t) * 3) * SZ + chan;
        cndv0 = cond[base]; cndv1 = cond[base + SZ]; cndv2 = cond[base + 2 * SZ];
        cvv = g_cv[lane]; fvv = g_fv[lane];
      }
      __syncthreads();
      float chold = 0.f;
      if (isC && lane < 16) chold = hlds[lane * 900 + chan];
      float acc[3][8];
#pragma unroll
      for (int r = 0; r < 3; ++r)
#pragma unroll
        for (int i = 0; i < 8; ++i) acc[r][i] = 0.f;
#pragma unroll
      for (int i = 0; i < 8; ++i) {
        const int b = b2 + 2 * i;
        const float* hb = hlds + b * 900 + 4 * l32;
        float4 h[7];
#pragma unroll
        for (int m = 0; m < 7; ++m) h[m] = *(const float4*)(hb + 128 * m);
#pragma unroll
        for (int r = 0; r < 3; ++r) {
          float s = acc[r][i];
#pragma unroll
          for (int m = 0; m < 7; ++m) {
            s = fmaf(w[r][m].x, h[m].x, s);
            s = fmaf(w[r][m].y, h[m].y, s);
            s = fmaf(w[r][m].z, h[m].z, s);
            s = fmaf(w[r][m].w, h[m].w, s);
          }
          acc[r][i] = s;
        }
      }
#pragma unroll
      for (int r = 0; r < 3; ++r)
#pragma unroll
        for (int i = 0; i < 8; ++i) {
          float v = acc[r][i];
          v += __shfl_xor(v, 2);
          v += __shfl_xor(v, 4);
          v += __shfl_xor(v, 8);
          v += __shfl_xor(v, 16);
          v += __shfl_xor(v, 32);
          acc[r][i] = v;
        }
      if (lane < 16) {
        const int b = lane, i = lane >> 1;  // b2 == lane&1 matches
        const float s0 = acc[0][i] + brow[0];
        const float s1 = acc[1][i] + brow[1];
        const float s2 = acc[2][i] + brow[2];
        if (isC) {
          const float cp0 = fmaf(cvv, wci0[0], fmaf(fvv, wci1[0], bcie[0])) + cndv0;
          const float cp1 = fmaf(cvv, wci0[1], fmaf(fvv, wci1[1], bcie[1])) + cndv1;
          const float cp2 = fmaf(cvv, wci0[2], fmaf(fvv, wci1[2], bcie[2])) + cndv2;
          const float rg = 1.f / (1.f + expf(-(cp0 + s0)));
          const float ug = 1.f / (1.f + expf(-(cp1 + s1)));
          const float eg = tanhf(fmaf(rg, s2, cp2));
          const float chn = ug * chold + (1.f - ug) * eg;
          hidbuf[(size_t)nxt * BB * SZ + b * SZ + chan] = chn;
        } else {
          g_hpf[(0 * HF + chan) * 16 + b] = s0;
          g_hpf[(1 * HF + chan) * 16 + b] = s1;
          g_hpf[(2 * HF + chan) * 16 + b] = s2;
        }
      }
      __threadfence();
      __syncthreads();
      if (tid == 0) atomicAdd(F1, 1u);
    }
  } else {
    // ================= sampler role: one batch each ==========
    const int b = wg - NCWG;
    float* slds = hlds;          // 448: staged ch / fh
    float* llds = hlds + 448;    // 256: logits
    float* redS = hlds + 704;    // 4
    int*   redI = (int*)(hlds + 712); // 4
    const int j1 = tid;
    const int j2 = tid + 256;
    const bool has2 = (j2 < HF); // tid < 192
    float wf[2][3][3], bfe[2][3];
#pragma unroll
    for (int g = 0; g < 3; ++g) {
      { const int rr = g * HF + j1;
        wf[0][g][0] = W_fi[3 * rr]; wf[0][g][1] = W_fi[3 * rr + 1]; wf[0][g][2] = W_fi[3 * rr + 2];
        bfe[0][g] = b_fi[rr] + gib[g * SZ + HF + j1]; }
      if (has2) { const int rr = g * HF + j2;
        wf[1][g][0] = W_fi[3 * rr]; wf[1][g][1] = W_fi[3 * rr + 1]; wf[1][g][2] = W_fi[3 * rr + 2];
        bfe[1][g] = b_fi[rr] + gib[g * SZ + HF + j2]; }
    }
    for (int t = 0; t < TT; ++t) {
      const int cur = t & 1, nxt = cur ^ 1;
      if (tid == 0) {
        while (__hip_atomic_load(F1, __ATOMIC_ACQUIRE, __HIP_MEMORY_SCOPE_AGENT)
               < (uint32_t)(NCWG * (t + 1))) {}
      }
      __syncthreads();
      const float cvOld = g_cv[b], fvOld = g_fv[b];
      if (tid < 112)
        *(float4*)&slds[4 * tid] = *(const float4*)&hidbuf[(size_t)nxt * BB * SZ + b * SZ + 4 * tid];
      __syncthreads();
      logits256(g_wbct, b_bc, slds, llds, tid);
      __syncthreads();
      // JAX key schedule (partitionable): key(1)=(0,1); kf=fold_in t; split foldlike:
      // k1 = tf2(kf,0,0), k2 = tf2(kf,0,1)
      const uint2 kf = tf2(0u, 1u, 0u, (uint32_t)t);
      const uint2 kA = tf2(kf.x, kf.y, 0u, 0u);
      const uint2 kB = tf2(kf.x, kf.y, 0u, 1u);
      const int sc = sample256(llds, kA.x, kA.y, b, tid, redS, redI);
      const float cvNew = (float)sc / 127.5f - 1.0f;
      if (tid == 0) { out[b * TT + t] = (float)sc; g_cv[b] = cvNew; }
      // fine gates
#pragma unroll
      for (int u = 0; u < 2; ++u) {
        if (u == 0 || has2) {
          const int j = u ? j2 : j1;
          const size_t cbase = (((size_t)b * TT + t) * 3) * SZ + HF + j;
          const float fp0 = fmaf(cvOld, wf[u][0][0], fmaf(fvOld, wf[u][0][1],
                             fmaf(cvNew, wf[u][0][2], bfe[u][0]))) + cond[cbase];
          const float fp1 = fmaf(cvOld, wf[u][1][0], fmaf(fvOld, wf[u][1][1],
                             fmaf(cvNew, wf[u][1][2], bfe[u][1]))) + cond[cbase + SZ];
          const float fp2 = fmaf(cvOld, wf[u][2][0], fmaf(fvOld, wf[u][2][1],
                             fmaf(cvNew, wf[u][2][2], bfe[u][2]))) + cond[cbase + 2 * SZ];
          const float h0 = g_hpf[(0 * HF + j) * 16 + b];
          const float h1 = g_hpf[(1 * HF + j) * 16 + b];
          const float h2 = g_hpf[(2 * HF + j) * 16 + b];
          const float fhold = hidbuf[(size_t)cur * BB * SZ + b * SZ + HF + j];
          const float rg = 1.f / (1.f + expf(-(fp0 + h0)));
          const float ug = 1.f / (1.f + expf(-(fp1 + h1)));
          const float eg = tanhf(fmaf(rg, h2, fp2));
          const float fhn = ug * fhold + (1.f - ug) * eg;
          hidbuf[(size_t)nxt * BB * SZ + b * SZ + HF + j] = fhn;
          slds[j] = fhn;
        }
      }
      __syncthreads();
      logits256(g_wbft, b_bf, slds, llds, tid);
      __syncthreads();
      const int sf = sample256(llds, kB.x, kB.y, b, tid, redS, redI);
      const float fvNew = (float)sf / 127.5f - 1.0f;
      if (tid == 0) { out[BB * TT + b * TT + t] = (float)sf; g_fv[b] = fvNew; }
      __threadfence();
      __syncthreads();
      if (tid == 0) atomicAdd(F2, 1u);
    }
    // final hidden: after t=999, state lives in buffer 0
    if (tid < 224) {
      const float* src = hidbuf + (size_t)b * SZ + 4 * tid;
      float* dst = out + 2 * BB * TT + (size_t)b * SZ + 4 * tid;
      *(float4*)dst = *(const float4*)src;
    }
  }
}

extern "C" void kernel_launch(void* const* d_in, const int* in_sizes, int n_in,
                              void* d_out, int out_size, void* d_ws, size_t ws_size,
                              hipStream_t stream) {
  (void)in_sizes; (void)n_in; (void)out_size; (void)d_ws; (void)ws_size;
  const float* cond = (const float*)d_in[0];
  const float* gib  = (const float*)d_in[1];
  const float* W_h  = (const float*)d_in[2];
  const float* b_h  = (const float*)d_in[3];
  const float* W_ci = (const float*)d_in[4];
  const float* b_ci = (const float*)d_in[5];
  const float* W_fi = (const float*)d_in[6];
  const float* b_fi = (const float*)d_in[7];
  const float* W_bc = (const float*)d_in[8];
  const float* b_bc = (const float*)d_in[9];
  const float* W_bf = (const float*)d_in[10];
  const float* b_bf = (const float*)d_in[11];
  float* out = (float*)d_out;
  wavernn_init<<<448, 256, 0, stream>>>(W_bc, W_bf);
  wavernn_main<<<NWG, 256, 0, stream>>>(cond, gib, W_h, b_h, W_ci, b_ci,
                                        W_fi, b_fi, b_bc, b_bf, out);
}

// Round 3
// 43666.809 us; speedup vs baseline: 3.6129x; 3.6129x over previous
//
#include <hip/hip_runtime.h>
#include <stdint.h>

#define BB 16
#define TT 1000
#define SZ 896
#define HF 448
#define NCWG 224
#define NSWG 16
#define NWG  240

// Persistent device-global state.
__device__ float g_wbct[HF * 256];       // W_bc transposed [448][256]  (read-only after init)
__device__ float g_wbft[HF * 256];       // W_bf transposed [448][256]  (read-only after init)
__device__ float g_hid[2 * BB * SZ];     // double-buffered hidden [2][16][896]  (cross-WG mutable)
__device__ float g_hpf[3 * HF * BB];     // fine-gate hp rows [3][448][16]       (cross-WG mutable)
__device__ float g_cv[BB];
__device__ float g_fv[BB];
__device__ uint32_t g_cdone[NCWG * 16];  // per-compute-WG step flags, 64B apart
__device__ uint32_t g_sdone[NSWG * 16];  // per-sampler-WG step flags, 64B apart

// ---- relaxed agent-scope (L3-coherent, cache-preserving) access helpers ----
__device__ __forceinline__ float aload(const float* p) {
  return __hip_atomic_load((float*)p, __ATOMIC_RELAXED, __HIP_MEMORY_SCOPE_AGENT);
}
__device__ __forceinline__ void astore(float* p, float v) {
  __hip_atomic_store(p, v, __ATOMIC_RELAXED, __HIP_MEMORY_SCOPE_AGENT);
}
__device__ __forceinline__ float2 aload2(const float* p) {
  unsigned long long u =
      __hip_atomic_load((unsigned long long*)p, __ATOMIC_RELAXED, __HIP_MEMORY_SCOPE_AGENT);
  float2 r;
  r.x = __uint_as_float((uint32_t)u);
  r.y = __uint_as_float((uint32_t)(u >> 32));
  return r;
}
__device__ __forceinline__ void waitFlag(uint32_t* f, uint32_t target) {
  while (__hip_atomic_load(f, __ATOMIC_RELAXED, __HIP_MEMORY_SCOPE_AGENT) < target)
    __builtin_amdgcn_s_sleep(1);
}

__device__ __forceinline__ uint32_t rotl32(uint32_t v, int d) {
  return (v << d) | (v >> (32 - d));
}

// JAX threefry2x32 block (20 rounds), bit-exact
__device__ __forceinline__ uint2 tf2(uint32_t k0, uint32_t k1, uint32_t x0, uint32_t x1) {
  const uint32_t k2 = k0 ^ k1 ^ 0x1BD11BDAu;
  x0 += k0; x1 += k1;
  x0 += x1; x1 = rotl32(x1,13); x1 ^= x0;
  x0 += x1; x1 = rotl32(x1,15); x1 ^= x0;
  x0 += x1; x1 = rotl32(x1,26); x1 ^= x0;
  x0 += x1; x1 = rotl32(x1, 6); x1 ^= x0;
  x0 += k1; x1 += k2 + 1u;
  x0 += x1; x1 = rotl32(x1,17); x1 ^= x0;
  x0 += x1; x1 = rotl32(x1,29); x1 ^= x0;
  x0 += x1; x1 = rotl32(x1,16); x1 ^= x0;
  x0 += x1; x1 = rotl32(x1,24); x1 ^= x0;
  x0 += k2; x1 += k0 + 2u;
  x0 += x1; x1 = rotl32(x1,13); x1 ^= x0;
  x0 += x1; x1 = rotl32(x1,15); x1 ^= x0;
  x0 += x1; x1 = rotl32(x1,26); x1 ^= x0;
  x0 += x1; x1 = rotl32(x1, 6); x1 ^= x0;
  x0 += k0; x1 += k1 + 3u;
  x0 += x1; x1 = rotl32(x1,17); x1 ^= x0;
  x0 += x1; x1 = rotl32(x1,29); x1 ^= x0;
  x0 += x1; x1 = rotl32(x1,16); x1 ^= x0;
  x0 += x1; x1 = rotl32(x1,24); x1 ^= x0;
  x0 += k1; x1 += k2 + 4u;
  x0 += x1; x1 = rotl32(x1,13); x1 ^= x0;
  x0 += x1; x1 = rotl32(x1,15); x1 ^= x0;
  x0 += x1; x1 = rotl32(x1,26); x1 ^= x0;
  x0 += x1; x1 = rotl32(x1, 6); x1 ^= x0;
  x0 += k2; x1 += k0 + 5u;
  return make_uint2(x0, x1);
}

__device__ __forceinline__ float gumbel_bits(uint32_t bits) {
  const float tiny = 1.17549435e-38f;
  float f = __uint_as_float((bits >> 9) | 0x3f800000u) - 1.0f;
  float u = fmaxf(tiny, f + tiny);
  return -logf(-logf(u));
}

// 256-bin logits: llds[n] = dot(vec[0:448], WT[:,n]) + bias[n]; WT is [448][256] (plain cached loads)
__device__ __forceinline__ void logits256(const float* __restrict__ WT,
                                          const float* __restrict__ bias,
                                          const float* __restrict__ vec,
                                          float* __restrict__ llds, int tid) {
  const int n4 = tid >> 2, q = tid & 3;
  float ax = 0.f, ay = 0.f, az = 0.f, aw = 0.f;
  const float* wp = WT + (size_t)(q * 112) * 256 + 4 * n4;
  const float* cp = vec + q * 112;
#pragma unroll 8
  for (int ii = 0; ii < 112; ++ii) {
    const float c = cp[ii];
    const float4 w4 = *(const float4*)(wp + (size_t)ii * 256);
    ax = fmaf(c, w4.x, ax); ay = fmaf(c, w4.y, ay);
    az = fmaf(c, w4.z, az); aw = fmaf(c, w4.w, aw);
  }
  ax += __shfl_xor(ax, 1); ax += __shfl_xor(ax, 2);
  ay += __shfl_xor(ay, 1); ay += __shfl_xor(ay, 2);
  az += __shfl_xor(az, 1); az += __shfl_xor(az, 2);
  aw += __shfl_xor(aw, 1); aw += __shfl_xor(aw, 2);
  if (q == 0) {
    llds[4 * n4 + 0] = ax + bias[4 * n4 + 0];
    llds[4 * n4 + 1] = ay + bias[4 * n4 + 1];
    llds[4 * n4 + 2] = az + bias[4 * n4 + 2];
    llds[4 * n4 + 3] = aw + bias[4 * n4 + 3];
  }
}

// categorical, partitionable threefry: counter = (hi=0, lo=b*256+n), bits = x0^x1.
__device__ __forceinline__ int sample256(const float* __restrict__ llds,
                                         uint32_t k0, uint32_t k1, int b, int tid,
                                         float* __restrict__ redS, int* __restrict__ redI) {
  const uint2 o = tf2(k0, k1, 0u, (uint32_t)(b * 256 + tid));
  const uint32_t bits = o.x ^ o.y;
  float s = llds[tid] + gumbel_bits(bits);
  int idx = tid;
#pragma unroll
  for (int mask = 1; mask < 64; mask <<= 1) {
    const float so = __shfl_xor(s, mask);
    const int   io = __shfl_xor(idx, mask);
    if (so > s || (so == s && io < idx)) { s = so; idx = io; }
  }
  if ((tid & 63) == 0) { redS[tid >> 6] = s; redI[tid >> 6] = idx; }
  __syncthreads();
  float bs = redS[0]; int bi = redI[0];
#pragma unroll
  for (int w = 1; w < 4; ++w) {
    const float so = redS[w]; const int io = redI[w];
    if (so > bs || (so == bs && io < bi)) { bs = so; bi = io; }
  }
  return bi;
}

__global__ __launch_bounds__(256, 1) void wavernn_init(const float* __restrict__ W_bc,
                                                       const float* __restrict__ W_bf) {
  const int idx = blockIdx.x * 256 + threadIdx.x;   // grid 448*256 = 114688
  const int ich = idx >> 8, n = idx & 255;
  g_wbct[idx] = W_bc[n * HF + ich];
  g_wbft[idx] = W_bf[n * HF + ich];
  if (idx < 2 * BB * SZ) g_hid[idx] = 0.f;
  if (idx < BB) { g_cv[idx] = -1.f; g_fv[idx] = -1.f; }
  if (idx < NCWG * 16) g_cdone[idx] = 0u;
  if (idx < NSWG * 16) g_sdone[idx] = 0u;
}

__global__ __launch_bounds__(256, 1) void wavernn_main(
    const float* __restrict__ cond, const float* __restrict__ gib,
    const float* __restrict__ W_h,  const float* __restrict__ b_h,
    const float* __restrict__ W_ci, const float* __restrict__ b_ci,
    const float* __restrict__ W_fi, const float* __restrict__ b_fi,
    const float* __restrict__ b_bc, const float* __restrict__ b_bf,
    float* __restrict__ out) {
  __shared__ float hlds[14400];   // compute: [16][900] padded hidden; sampler: aliased scratch
  const int wg = blockIdx.x, tid = threadIdx.x;

  if (wg < NCWG) {
    // ================= compute role ==========
    const int wave = tid >> 6, lane = tid & 63;
    const int l32 = lane >> 1, b2 = lane & 1;
    const bool isC = wave < 2;
    const int chan = (wg << 1) | (wave & 1);           // 0..447
    const int rb = isC ? chan : (HF + chan);
    float4 w[3][7];                                     // W_h rows in registers, permanent
    float brow[3];
#pragma unroll
    for (int r = 0; r < 3; ++r) {
      const int row = r * SZ + rb;
      brow[r] = b_h[row];
#pragma unroll
      for (int m = 0; m < 7; ++m)
        w[r][m] = *(const float4*)&W_h[(size_t)row * SZ + 4 * l32 + 128 * m];
    }
    float wci0[3], wci1[3], bcie[3];
    if (isC) {
#pragma unroll
      for (int g = 0; g < 3; ++g) {
        const int rr = g * HF + chan;
        wci0[g] = W_ci[2 * rr]; wci1[g] = W_ci[2 * rr + 1];
        bcie[g] = b_ci[rr] + gib[g * SZ + chan];
      }
    }
    // prefetch cond for t=0
    float pc0 = 0.f, pc1 = 0.f, pc2 = 0.f;
    if (isC && lane < 16) {
      const size_t base = (((size_t)lane * TT) * 3) * SZ + chan;
      pc0 = cond[base]; pc1 = cond[base + SZ]; pc2 = cond[base + 2 * SZ];
    }
    for (int t = 0; t < TT; ++t) {
      const int cur = t & 1, nxt = cur ^ 1;
      if (t > 0 && tid < NSWG) waitFlag(&g_sdone[tid * 16], (uint32_t)t);
      __syncthreads();
      { // stage hidden[cur] -> LDS via L3-coherent float2 loads, interleaved (conflict-free)
        const int sb = tid >> 4, sl = tid & 15;
        const float* src = g_hid + (size_t)cur * BB * SZ + sb * SZ;
        float* dst = hlds + sb * 900;
#pragma unroll
        for (int m = 0; m < 28; ++m) {
          const int o = 2 * (sl + 16 * m);
          const float2 v = aload2(src + o);
          *(float2*)(dst + o) = v;
        }
      }
      float cvv = 0.f, fvv = 0.f;
      if (isC && lane < 16) { cvv = aload(&g_cv[lane]); fvv = aload(&g_fv[lane]); }
      __syncthreads();
      float chold = 0.f;
      if (isC && lane < 16) chold = hlds[lane * 900 + chan];
      float acc[3][8];
#pragma unroll
      for (int r = 0; r < 3; ++r)
#pragma unroll
        for (int i = 0; i < 8; ++i) acc[r][i] = 0.f;
#pragma unroll
      for (int i = 0; i < 8; ++i) {
        const int b = b2 + 2 * i;
        const float* hb = hlds + b * 900 + 4 * l32;
        float4 h[7];
#pragma unroll
        for (int m = 0; m < 7; ++m) h[m] = *(const float4*)(hb + 128 * m);
#pragma unroll
        for (int r = 0; r < 3; ++r) {
          float s = acc[r][i];
#pragma unroll
          for (int m = 0; m < 7; ++m) {
            s = fmaf(w[r][m].x, h[m].x, s);
            s = fmaf(w[r][m].y, h[m].y, s);
            s = fmaf(w[r][m].z, h[m].z, s);
            s = fmaf(w[r][m].w, h[m].w, s);
          }
          acc[r][i] = s;
        }
      }
#pragma unroll
      for (int r = 0; r < 3; ++r)
#pragma unroll
        for (int i = 0; i < 8; ++i) {
          float v = acc[r][i];
          v += __shfl_xor(v, 2);
          v += __shfl_xor(v, 4);
          v += __shfl_xor(v, 8);
          v += __shfl_xor(v, 16);
          v += __shfl_xor(v, 32);
          acc[r][i] = v;
        }
      if (lane < 16) {
        const int b = lane, i = lane >> 1;
        const float s0 = acc[0][i] + brow[0];
        const float s1 = acc[1][i] + brow[1];
        const float s2 = acc[2][i] + brow[2];
        if (isC) {
          const float cp0 = fmaf(cvv, wci0[0], fmaf(fvv, wci1[0], bcie[0])) + pc0;
          const float cp1 = fmaf(cvv, wci0[1], fmaf(fvv, wci1[1], bcie[1])) + pc1;
          const float cp2 = fmaf(cvv, wci0[2], fmaf(fvv, wci1[2], bcie[2])) + pc2;
          const float rg = 1.f / (1.f + expf(-(cp0 + s0)));
          const float ug = 1.f / (1.f + expf(-(cp1 + s1)));
          const float eg = tanhf(fmaf(rg, s2, cp2));
          const float chn = ug * chold + (1.f - ug) * eg;
          astore(&g_hid[(size_t)nxt * BB * SZ + b * SZ + chan], chn);
        } else {
          astore(&g_hpf[(0 * HF + chan) * 16 + b], s0);
          astore(&g_hpf[(1 * HF + chan) * 16 + b], s1);
          astore(&g_hpf[(2 * HF + chan) * 16 + b], s2);
        }
      }
      __syncthreads();   // drains all waves' sc-stores (vmcnt0 before barrier)
      if (tid == 0)
        __hip_atomic_store(&g_cdone[wg * 16], (uint32_t)(t + 1),
                           __ATOMIC_RELAXED, __HIP_MEMORY_SCOPE_AGENT);
      // prefetch cond for t+1 (off critical path)
      if (isC && lane < 16 && t + 1 < TT) {
        const size_t base = (((size_t)lane * TT + (t + 1)) * 3) * SZ + chan;
        pc0 = cond[base]; pc1 = cond[base + SZ]; pc2 = cond[base + 2 * SZ];
      }
    }
  } else {
    // ================= sampler role: one batch each ==========
    const int b = wg - NCWG;
    float* slds = hlds;          // 448: staged ch / fh
    float* llds = hlds + 448;    // 256: logits
    float* redS = hlds + 704;    // 4
    int*   redI = (int*)(hlds + 712); // 4
    const int j1 = tid;
    const int j2 = tid + 256;
    const bool has2 = (j2 < HF); // tid < 192
    float wf[2][3][3], bfe[2][3];
#pragma unroll
    for (int g = 0; g < 3; ++g) {
      { const int rr = g * HF + j1;
        wf[0][g][0] = W_fi[3 * rr]; wf[0][g][1] = W_fi[3 * rr + 1]; wf[0][g][2] = W_fi[3 * rr + 2];
        bfe[0][g] = b_fi[rr] + gib[g * SZ + HF + j1]; }
      if (has2) { const int rr = g * HF + j2;
        wf[1][g][0] = W_fi[3 * rr]; wf[1][g][1] = W_fi[3 * rr + 1]; wf[1][g][2] = W_fi[3 * rr + 2];
        bfe[1][g] = b_fi[rr] + gib[g * SZ + HF + j2]; }
    }
    // prefetch fine-cond for t=0
    float cpre[2][3];
#pragma unroll
    for (int u = 0; u < 2; ++u)
      if (u == 0 || has2) {
        const int j = u ? j2 : j1;
        const size_t cbase = (((size_t)b * TT) * 3) * SZ + HF + j;
        cpre[u][0] = cond[cbase]; cpre[u][1] = cond[cbase + SZ]; cpre[u][2] = cond[cbase + 2 * SZ];
      }
    for (int t = 0; t < TT; ++t) {
      const int cur = t & 1, nxt = cur ^ 1;
      if (tid < NCWG) waitFlag(&g_cdone[tid * 16], (uint32_t)(t + 1));
      __syncthreads();
      const float cvOld = aload(&g_cv[b]), fvOld = aload(&g_fv[b]);
      if (tid < 224) {
        const float2 v = aload2(&g_hid[(size_t)nxt * BB * SZ + b * SZ + 2 * tid]);
        slds[2 * tid] = v.x; slds[2 * tid + 1] = v.y;
      }
      __syncthreads();
      logits256(g_wbct, b_bc, slds, llds, tid);
      __syncthreads();
      // JAX key schedule (partitionable)
      const uint2 kf = tf2(0u, 1u, 0u, (uint32_t)t);
      const uint2 kA = tf2(kf.x, kf.y, 0u, 0u);
      const uint2 kB = tf2(kf.x, kf.y, 0u, 1u);
      const int sc = sample256(llds, kA.x, kA.y, b, tid, redS, redI);
      const float cvNew = (float)sc / 127.5f - 1.0f;
      if (tid == 0) { out[b * TT + t] = (float)sc; astore(&g_cv[b], cvNew); }
      // fine gates
#pragma unroll
      for (int u = 0; u < 2; ++u) {
        if (u == 0 || has2) {
          const int j = u ? j2 : j1;
          const float fp0 = fmaf(cvOld, wf[u][0][0], fmaf(fvOld, wf[u][0][1],
                             fmaf(cvNew, wf[u][0][2], bfe[u][0]))) + cpre[u][0];
          const float fp1 = fmaf(cvOld, wf[u][1][0], fmaf(fvOld, wf[u][1][1],
                             fmaf(cvNew, wf[u][1][2], bfe[u][1]))) + cpre[u][1];
          const float fp2 = fmaf(cvOld, wf[u][2][0], fmaf(fvOld, wf[u][2][1],
                             fmaf(cvNew, wf[u][2][2], bfe[u][2]))) + cpre[u][2];
          const float h0 = aload(&g_hpf[(0 * HF + j) * 16 + b]);
          const float h1 = aload(&g_hpf[(1 * HF + j) * 16 + b]);
          const float h2 = aload(&g_hpf[(2 * HF + j) * 16 + b]);
          const float fhold = aload(&g_hid[(size_t)cur * BB * SZ + b * SZ + HF + j]);
          const float rg = 1.f / (1.f + expf(-(fp0 + h0)));
          const float ug = 1.f / (1.f + expf(-(fp1 + h1)));
          const float eg = tanhf(fmaf(rg, h2, fp2));
          const float fhn = ug * fhold + (1.f - ug) * eg;
          astore(&g_hid[(size_t)nxt * BB * SZ + b * SZ + HF + j], fhn);
          slds[j] = fhn;
        }
      }
      __syncthreads();
      logits256(g_wbft, b_bf, slds, llds, tid);
      __syncthreads();
      const int sf = sample256(llds, kB.x, kB.y, b, tid, redS, redI);
      const float fvNew = (float)sf / 127.5f - 1.0f;
      if (tid == 0) { out[BB * TT + b * TT + t] = (float)sf; astore(&g_fv[b], fvNew); }
      __syncthreads();   // drains fine-hid sc-stores of all waves
      if (tid == 0)
        __hip_atomic_store(&g_sdone[b * 16], (uint32_t)(t + 1),
                           __ATOMIC_RELAXED, __HIP_MEMORY_SCOPE_AGENT);
      // prefetch fine-cond for t+1
      if (t + 1 < TT) {
#pragma unroll
        for (int u = 0; u < 2; ++u)
          if (u == 0 || has2) {
            const int j = u ? j2 : j1;
            const size_t cbase = (((size_t)b * TT + (t + 1)) * 3) * SZ + HF + j;
            cpre[u][0] = cond[cbase]; cpre[u][1] = cond[cbase + SZ];
            cpre[u][2] = cond[cbase + 2 * SZ];
          }
      }
    }
    // final hidden: after t=999, state lives in buffer 0
    if (tid < 224) {
      const float2 v0 = aload2(&g_hid[(size_t)b * SZ + 4 * tid]);
      const float2 v1 = aload2(&g_hid[(size_t)b * SZ + 4 * tid + 2]);
      float* dst = out + 2 * BB * TT + (size_t)b * SZ + 4 * tid;
      dst[0] = v0.x; dst[1] = v0.y; dst[2] = v1.x; dst[3] = v1.y;
    }
  }
}

extern "C" void kernel_launch(void* const* d_in, const int* in_sizes, int n_in,
                              void* d_out, int out_size, void* d_ws, size_t ws_size,
                              hipStream_t stream) {
  (void)in_sizes; (void)n_in; (void)out_size; (void)d_ws; (void)ws_size;
  const float* cond = (const float*)d_in[0];
  const float* gib  = (const float*)d_in[1];
  const float* W_h  = (const float*)d_in[2];
  const float* b_h  = (const float*)d_in[3];
  const float* W_ci = (const float*)d_in[4];
  const float* b_ci = (const float*)d_in[5];
  const float* W_fi = (const float*)d_in[6];
  const float* b_fi = (const float*)d_in[7];
  const float* W_bc = (const float*)d_in[8];
  const float* b_bc = (const float*)d_in[9];
  const float* W_bf = (const float*)d_in[10];
  const float* b_bf = (const float*)d_in[11];
  float* out = (float*)d_out;
  wavernn_init<<<448, 256, 0, stream>>>(W_bc, W_bf);
  wavernn_main<<<NWG, 256, 0, stream>>>(cond, gib, W_h, b_h, W_ci, b_ci,
                                        W_fi, b_fi, b_bc, b_bf, out);
}

// Round 4
// 34049.048 us; speedup vs baseline: 4.6334x; 1.2825x over previous
//
#include <hip/hip_runtime.h>
#include <stdint.h>

#define BB 16
#define TT 1000
#define SZ 896
#define HF 448
#define NCWG 224
#define NSWG 16
#define NWG  240

typedef float f32x4 __attribute__((ext_vector_type(4)));
typedef float f32x2 __attribute__((ext_vector_type(2)));

// Persistent device-global state.
__device__ float g_wbct[HF * 256];       // W_bc^T [448][256] (read-only after init)
__device__ float g_wbft[HF * 256];       // W_bf^T [448][256]
__device__ float g_hid[2 * BB * SZ];     // double-buffered hidden [2][16][896]
__device__ float g_hpf4[HF * BB * 4];    // fine hp rows [448][16][4] = {h_r,h_u,h_e,pad}
__device__ uint32_t g_cdone[NCWG * 16];  // compute flags (64B apart), value = t+1
__device__ uint32_t g_sdA[NSWG * 16];    // sampler flag A: ((t+1)<<8)|sc  (fh published)
__device__ uint32_t g_sdB[NSWG * 16];    // sampler flag B: ((t+1)<<8)|sf

// ---- pipelined coherent (L2-bypassing) loads/stores ----
__device__ __forceinline__ void cload7x4(const float* p, f32x4& a0, f32x4& a1, f32x4& a2,
                                         f32x4& a3, f32x4& a4, f32x4& a5, f32x4& a6) {
  asm volatile(
      "global_load_dwordx4 %0, %7, off sc0 sc1\n\t"
      "global_load_dwordx4 %1, %7, off offset:16 sc0 sc1\n\t"
      "global_load_dwordx4 %2, %7, off offset:32 sc0 sc1\n\t"
      "global_load_dwordx4 %3, %7, off offset:48 sc0 sc1\n\t"
      "global_load_dwordx4 %4, %7, off offset:64 sc0 sc1\n\t"
      "global_load_dwordx4 %5, %7, off offset:80 sc0 sc1\n\t"
      "global_load_dwordx4 %6, %7, off offset:96 sc0 sc1\n\t"
      "s_waitcnt vmcnt(0)"
      : "=&v"(a0), "=&v"(a1), "=&v"(a2), "=&v"(a3), "=&v"(a4), "=&v"(a5), "=&v"(a6)
      : "v"(p) : "memory");
}
__device__ __forceinline__ void cload3x4(const float* p0, const float* p1, const float* p2,
                                         f32x4& a, f32x4& b, f32x4& c) {
  asm volatile(
      "global_load_dwordx4 %0, %3, off sc0 sc1\n\t"
      "global_load_dwordx4 %1, %4, off sc0 sc1\n\t"
      "global_load_dwordx4 %2, %5, off sc0 sc1\n\t"
      "s_waitcnt vmcnt(0)"
      : "=&v"(a), "=&v"(b), "=&v"(c)
      : "v"(p0), "v"(p1), "v"(p2) : "memory");
}
__device__ __forceinline__ void cstore1d(float* p, float v) {
  asm volatile("global_store_dword %0, %1, off sc0 sc1\n\ts_waitcnt vmcnt(0)"
               :: "v"(p), "v"(v) : "memory");
}
__device__ __forceinline__ void cstore2d(float* p, f32x2 v) {
  asm volatile("global_store_dwordx2 %0, %1, off sc0 sc1\n\ts_waitcnt vmcnt(0)"
               :: "v"(p), "v"(v) : "memory");
}
__device__ __forceinline__ void cstore4d(float* p, f32x4 v) {
  asm volatile("global_store_dwordx4 %0, %1, off sc0 sc1\n\ts_waitcnt vmcnt(0)"
               :: "v"(p), "v"(v) : "memory");
}

__device__ __forceinline__ void waitFlag(uint32_t* f, uint32_t target) {
  while (__hip_atomic_load(f, __ATOMIC_RELAXED, __HIP_MEMORY_SCOPE_AGENT) < target)
    __builtin_amdgcn_s_sleep(1);
}
__device__ __forceinline__ void waitFlagA(uint32_t* f, uint32_t target) {
  while (__hip_atomic_load(f, __ATOMIC_RELAXED, __HIP_MEMORY_SCOPE_AGENT) < target)
    __builtin_amdgcn_s_sleep(4);
}
__device__ __forceinline__ uint32_t waitFlag2(uint32_t* f, uint32_t target) {
  uint32_t v;
  while (((v = __hip_atomic_load(f, __ATOMIC_RELAXED, __HIP_MEMORY_SCOPE_AGENT)) >> 8) < target)
    __builtin_amdgcn_s_sleep(1);
  return v;
}

__device__ __forceinline__ uint32_t rotl32(uint32_t v, int d) {
  return (v << d) | (v >> (32 - d));
}

// JAX threefry2x32 (20 rounds), bit-exact
__device__ __forceinline__ uint2 tf2(uint32_t k0, uint32_t k1, uint32_t x0, uint32_t x1) {
  const uint32_t k2 = k0 ^ k1 ^ 0x1BD11BDAu;
  x0 += k0; x1 += k1;
  x0 += x1; x1 = rotl32(x1,13); x1 ^= x0;
  x0 += x1; x1 = rotl32(x1,15); x1 ^= x0;
  x0 += x1; x1 = rotl32(x1,26); x1 ^= x0;
  x0 += x1; x1 = rotl32(x1, 6); x1 ^= x0;
  x0 += k1; x1 += k2 + 1u;
  x0 += x1; x1 = rotl32(x1,17); x1 ^= x0;
  x0 += x1; x1 = rotl32(x1,29); x1 ^= x0;
  x0 += x1; x1 = rotl32(x1,16); x1 ^= x0;
  x0 += x1; x1 = rotl32(x1,24); x1 ^= x0;
  x0 += k2; x1 += k0 + 2u;
  x0 += x1; x1 = rotl32(x1,13); x1 ^= x0;
  x0 += x1; x1 = rotl32(x1,15); x1 ^= x0;
  x0 += x1; x1 = rotl32(x1,26); x1 ^= x0;
  x0 += x1; x1 = rotl32(x1, 6); x1 ^= x0;
  x0 += k0; x1 += k1 + 3u;
  x0 += x1; x1 = rotl32(x1,17); x1 ^= x0;
  x0 += x1; x1 = rotl32(x1,29); x1 ^= x0;
  x0 += x1; x1 = rotl32(x1,16); x1 ^= x0;
  x0 += x1; x1 = rotl32(x1,24); x1 ^= x0;
  x0 += k1; x1 += k2 + 4u;
  x0 += x1; x1 = rotl32(x1,13); x1 ^= x0;
  x0 += x1; x1 = rotl32(x1,15); x1 ^= x0;
  x0 += x1; x1 = rotl32(x1,26); x1 ^= x0;
  x0 += x1; x1 = rotl32(x1, 6); x1 ^= x0;
  x0 += k2; x1 += k0 + 5u;
  return make_uint2(x0, x1);
}

__device__ __forceinline__ float gumbel_bits(uint32_t bits) {
  const float tiny = 1.17549435e-38f;
  float f = __uint_as_float((bits >> 9) | 0x3f800000u) - 1.0f;
  float u = fmaxf(tiny, f + tiny);
  return -logf(-logf(u));
}

// 256-bin logits: llds[n] = dot(vec[0:448], WT[:,n]) + bias[n]; WT is [448][256]
__device__ __forceinline__ void logits256(const float* __restrict__ WT,
                                          const float* __restrict__ bias,
                                          const float* __restrict__ vec,
                                          float* __restrict__ llds, int tid) {
  const int n4 = tid >> 2, q = tid & 3;
  float ax = 0.f, ay = 0.f, az = 0.f, aw = 0.f;
  const float* wp = WT + (size_t)(q * 112) * 256 + 4 * n4;
  const float* cp = vec + q * 112;
#pragma unroll 8
  for (int ii = 0; ii < 112; ++ii) {
    const float c = cp[ii];
    const float4 w4 = *(const float4*)(wp + (size_t)ii * 256);
    ax = fmaf(c, w4.x, ax); ay = fmaf(c, w4.y, ay);
    az = fmaf(c, w4.z, az); aw = fmaf(c, w4.w, aw);
  }
  ax += __shfl_xor(ax, 1); ax += __shfl_xor(ax, 2);
  ay += __shfl_xor(ay, 1); ay += __shfl_xor(ay, 2);
  az += __shfl_xor(az, 1); az += __shfl_xor(az, 2);
  aw += __shfl_xor(aw, 1); aw += __shfl_xor(aw, 2);
  if (q == 0) {
    llds[4 * n4 + 0] = ax + bias[4 * n4 + 0];
    llds[4 * n4 + 1] = ay + bias[4 * n4 + 1];
    llds[4 * n4 + 2] = az + bias[4 * n4 + 2];
    llds[4 * n4 + 3] = aw + bias[4 * n4 + 3];
  }
}

// categorical, partitionable threefry: counter = (0, b*256+n), bits = x0^x1
__device__ __forceinline__ int sample256(const float* __restrict__ llds,
                                         uint32_t k0, uint32_t k1, int b, int tid,
                                         float* __restrict__ redS, int* __restrict__ redI) {
  const uint2 o = tf2(k0, k1, 0u, (uint32_t)(b * 256 + tid));
  const uint32_t bits = o.x ^ o.y;
  float s = llds[tid] + gumbel_bits(bits);
  int idx = tid;
#pragma unroll
  for (int mask = 1; mask < 64; mask <<= 1) {
    const float so = __shfl_xor(s, mask);
    const int   io = __shfl_xor(idx, mask);
    if (so > s || (so == s && io < idx)) { s = so; idx = io; }
  }
  if ((tid & 63) == 0) { redS[tid >> 6] = s; redI[tid >> 6] = idx; }
  __syncthreads();
  float bs = redS[0]; int bi = redI[0];
#pragma unroll
  for (int w = 1; w < 4; ++w) {
    const float so = redS[w]; const int io = redI[w];
    if (so > bs || (so == bs && io < bi)) { bs = so; bi = io; }
  }
  return bi;
}

__global__ __launch_bounds__(256, 1) void wavernn_init(const float* __restrict__ W_bc,
                                                       const float* __restrict__ W_bf) {
  const int idx = blockIdx.x * 256 + threadIdx.x;   // grid 448*256 = 114688
  const int ich = idx >> 8, n = idx & 255;
  g_wbct[idx] = W_bc[n * HF + ich];
  g_wbft[idx] = W_bf[n * HF + ich];
  if (idx < 2 * BB * SZ) g_hid[idx] = 0.f;
  if (idx < NCWG * 16) g_cdone[idx] = 0u;
  if (idx < NSWG * 16) { g_sdA[idx] = 0u; g_sdB[idx] = 0u; }
}

__global__ __launch_bounds__(256, 1) void wavernn_main(
    const float* __restrict__ cond, const float* __restrict__ gib,
    const float* __restrict__ W_h,  const float* __restrict__ b_h,
    const float* __restrict__ W_ci, const float* __restrict__ b_ci,
    const float* __restrict__ W_fi, const float* __restrict__ b_fi,
    const float* __restrict__ b_bc, const float* __restrict__ b_bf,
    float* __restrict__ out) {
  __shared__ float hlds[14400];   // compute: [16][900]; sampler: slds/flds/llds/red
  __shared__ int smcv[16], smfv[16];
  const int wg = blockIdx.x, tid = threadIdx.x;

  if (wg < NCWG) {
    // ================= compute role =================
    const int wave = tid >> 6, lane = tid & 63;
    const int l32 = lane >> 1, b2 = lane & 1;
    const bool isC = wave < 2;
    const int chan = (wg << 1) | (wave & 1);           // 0..447
    const int rb = isC ? chan : (HF + chan);
    float4 w[3][7];
    float brow[3];
#pragma unroll
    for (int r = 0; r < 3; ++r) {
      const int row = r * SZ + rb;
      brow[r] = b_h[row];
#pragma unroll
      for (int m = 0; m < 7; ++m)
        w[r][m] = *(const float4*)&W_h[(size_t)row * SZ + 4 * l32 + 128 * m];
    }
    float wci0[3], wci1[3], bcie[3];
    if (isC) {
#pragma unroll
      for (int g = 0; g < 3; ++g) {
        const int rr = g * HF + chan;
        wci0[g] = W_ci[2 * rr]; wci1[g] = W_ci[2 * rr + 1];
        bcie[g] = b_ci[rr] + gib[g * SZ + chan];
      }
    }
    float pc0 = 0.f, pc1 = 0.f, pc2 = 0.f;
    if (isC && lane < 16) {
      const size_t base = (((size_t)lane * TT) * 3) * SZ + chan;
      pc0 = cond[base]; pc1 = cond[base + SZ]; pc2 = cond[base + 2 * SZ];
    }
    float chreg = 0.f;   // ch_{t-1}[chan][b=lane] held locally
    const int sb = tid >> 4, sl = tid & 15;

    for (int t = 0; t < TT; ++t) {
      const int p = (t & 1) ^ 1;   // hidden_{t-1} buffer
      const int q = t & 1;         // ch_t / hpf_t destination
      // ---- Phase A: all compute WGs published ch_{t-1}; stage coarse half, partial matvec
      if (tid < NCWG) waitFlagA(&g_cdone[tid * 16], (uint32_t)t);
      __syncthreads();
      {
        const float* src = g_hid + (size_t)p * BB * SZ + sb * SZ + 28 * sl;
        f32x4 a0, a1, a2, a3, a4, a5, a6;
        cload7x4(src, a0, a1, a2, a3, a4, a5, a6);
        float* dst = hlds + sb * 900 + 28 * sl;
        *(f32x4*)(dst)      = a0; *(f32x4*)(dst + 4)  = a1;
        *(f32x4*)(dst + 8)  = a2; *(f32x4*)(dst + 12) = a3;
        *(f32x4*)(dst + 16) = a4; *(f32x4*)(dst + 20) = a5;
        *(f32x4*)(dst + 24) = a6;
      }
      __syncthreads();
      float acc[3][8];
#pragma unroll
      for (int r = 0; r < 3; ++r)
#pragma unroll
        for (int i = 0; i < 8; ++i) acc[r][i] = 0.f;
#pragma unroll
      for (int i = 0; i < 8; ++i) {
        const int b = b2 + 2 * i;
        const float* hb = hlds + b * 900 + 4 * l32;
        const float4 h0 = *(const float4*)(hb);
        const float4 h1 = *(const float4*)(hb + 128);
        const float4 h2 = *(const float4*)(hb + 256);
#pragma unroll
        for (int r = 0; r < 3; ++r) {
          float s = acc[r][i];
          s = fmaf(w[r][0].x, h0.x, s); s = fmaf(w[r][0].y, h0.y, s);
          s = fmaf(w[r][0].z, h0.z, s); s = fmaf(w[r][0].w, h0.w, s);
          s = fmaf(w[r][1].x, h1.x, s); s = fmaf(w[r][1].y, h1.y, s);
          s = fmaf(w[r][1].z, h1.z, s); s = fmaf(w[r][1].w, h1.w, s);
          s = fmaf(w[r][2].x, h2.x, s); s = fmaf(w[r][2].y, h2.y, s);
          s = fmaf(w[r][2].z, h2.z, s); s = fmaf(w[r][2].w, h2.w, s);
          acc[r][i] = s;
        }
        if (l32 < 16) {   // m=3 straddles the 448 boundary: k=384+4*l32 < 448
          const float4 h3 = *(const float4*)(hb + 384);
#pragma unroll
          for (int r = 0; r < 3; ++r) {
            float s = acc[r][i];
            s = fmaf(w[r][3].x, h3.x, s); s = fmaf(w[r][3].y, h3.y, s);
            s = fmaf(w[r][3].z, h3.z, s); s = fmaf(w[r][3].w, h3.w, s);
            acc[r][i] = s;
          }
        }
      }
      // ---- Phase B1: fh_{t-1} published; stage fine half, finish matvec
      if (tid < NSWG) {
        const uint32_t vA = waitFlag2(&g_sdA[tid * 16], (uint32_t)t);
        smcv[tid] = (int)(vA & 255u);
      }
      __syncthreads();
      {
        const float* src = g_hid + (size_t)p * BB * SZ + sb * SZ + HF + 28 * sl;
        f32x4 a0, a1, a2, a3, a4, a5, a6;
        cload7x4(src, a0, a1, a2, a3, a4, a5, a6);
        float* dst = hlds + sb * 900 + HF + 28 * sl;
        *(f32x4*)(dst)      = a0; *(f32x4*)(dst + 4)  = a1;
        *(f32x4*)(dst + 8)  = a2; *(f32x4*)(dst + 12) = a3;
        *(f32x4*)(dst + 16) = a4; *(f32x4*)(dst + 20) = a5;
        *(f32x4*)(dst + 24) = a6;
      }
      __syncthreads();
#pragma unroll
      for (int i = 0; i < 8; ++i) {
        const int b = b2 + 2 * i;
        const float* hb = hlds + b * 900 + 4 * l32;
        if (l32 >= 16) {   // m=3 fine part: k=384+4*l32 >= 448
          const float4 h3 = *(const float4*)(hb + 384);
#pragma unroll
          for (int r = 0; r < 3; ++r) {
            float s = acc[r][i];
            s = fmaf(w[r][3].x, h3.x, s); s = fmaf(w[r][3].y, h3.y, s);
            s = fmaf(w[r][3].z, h3.z, s); s = fmaf(w[r][3].w, h3.w, s);
            acc[r][i] = s;
          }
        }
        const float4 h4 = *(const float4*)(hb + 512);
        const float4 h5 = *(const float4*)(hb + 640);
        const float4 h6 = *(const float4*)(hb + 768);
#pragma unroll
        for (int r = 0; r < 3; ++r) {
          float s = acc[r][i];
          s = fmaf(w[r][4].x, h4.x, s); s = fmaf(w[r][4].y, h4.y, s);
          s = fmaf(w[r][4].z, h4.z, s); s = fmaf(w[r][4].w, h4.w, s);
          s = fmaf(w[r][5].x, h5.x, s); s = fmaf(w[r][5].y, h5.y, s);
          s = fmaf(w[r][5].z, h5.z, s); s = fmaf(w[r][5].w, h5.w, s);
          s = fmaf(w[r][6].x, h6.x, s); s = fmaf(w[r][6].y, h6.y, s);
          s = fmaf(w[r][6].z, h6.z, s); s = fmaf(w[r][6].w, h6.w, s);
          acc[r][i] = s;
        }
      }
#pragma unroll
      for (int r = 0; r < 3; ++r)
#pragma unroll
        for (int i = 0; i < 8; ++i) {
          float v = acc[r][i];
          v += __shfl_xor(v, 2);
          v += __shfl_xor(v, 4);
          v += __shfl_xor(v, 8);
          v += __shfl_xor(v, 16);
          v += __shfl_xor(v, 32);
          acc[r][i] = v;
        }
      // ---- Phase B2: fv_{t-1} from flag B; gates + publish
      if (tid < NSWG) {
        const uint32_t vB = waitFlag2(&g_sdB[tid * 16], (uint32_t)t);
        smfv[tid] = (int)(vB & 255u);
      }
      __syncthreads();
      if (lane < 16) {
        const int bb = lane, i = lane >> 1;
        const float s0 = acc[0][i] + brow[0];
        const float s1 = acc[1][i] + brow[1];
        const float s2 = acc[2][i] + brow[2];
        if (isC) {
          const float cvv = (float)smcv[bb] / 127.5f - 1.0f;
          const float fvv = (float)smfv[bb] / 127.5f - 1.0f;
          const float cp0 = fmaf(cvv, wci0[0], fmaf(fvv, wci1[0], bcie[0])) + pc0;
          const float cp1 = fmaf(cvv, wci0[1], fmaf(fvv, wci1[1], bcie[1])) + pc1;
          const float cp2 = fmaf(cvv, wci0[2], fmaf(fvv, wci1[2], bcie[2])) + pc2;
          const float rg = 1.f / (1.f + expf(-(cp0 + s0)));
          const float ug = 1.f / (1.f + expf(-(cp1 + s1)));
          const float eg = tanhf(fmaf(rg, s2, cp2));
          const float chn = ug * chreg + (1.f - ug) * eg;
          chreg = chn;
          cstore1d(&g_hid[(size_t)q * BB * SZ + bb * SZ + chan], chn);
        } else {
          f32x4 hv; hv.x = s0; hv.y = s1; hv.z = s2; hv.w = 0.f;
          cstore4d(&g_hpf4[((size_t)chan * 16 + bb) * 4], hv);
        }
      }
      __syncthreads();
      if (tid == 0)
        __hip_atomic_store(&g_cdone[wg * 16], (uint32_t)(t + 1),
                           __ATOMIC_RELAXED, __HIP_MEMORY_SCOPE_AGENT);
      if (isC && lane < 16 && t + 1 < TT) {
        const size_t base = (((size_t)lane * TT + (t + 1)) * 3) * SZ + chan;
        pc0 = cond[base]; pc1 = cond[base + SZ]; pc2 = cond[base + 2 * SZ];
      }
    }
  } else {
    // ================= sampler role: one batch each =================
    const int b = wg - NCWG;
    float* slds = hlds;                 // [448] staged ch_t
    float* flds = hlds + 448;           // [448] fh (persistent, local)
    float* llds = hlds + 896;           // [256]
    float* redS = hlds + 1152;          // [4]
    int*   redI = (int*)(hlds + 1156);  // [4]
    const int j1 = tid;
    const bool has2 = (tid + 256 < HF);
    const int j2 = has2 ? (tid + 256) : (HF - 1);
    if (tid < 224) { flds[tid] = 0.f; flds[tid + 224] = 0.f; }
    float wf[2][3][3], bfe[2][3];
#pragma unroll
    for (int g = 0; g < 3; ++g) {
      { const int rr = g * HF + j1;
        wf[0][g][0] = W_fi[3 * rr]; wf[0][g][1] = W_fi[3 * rr + 1]; wf[0][g][2] = W_fi[3 * rr + 2];
        bfe[0][g] = b_fi[rr] + gib[g * SZ + HF + j1]; }
      { const int rr = g * HF + j2;
        wf[1][g][0] = W_fi[3 * rr]; wf[1][g][1] = W_fi[3 * rr + 1]; wf[1][g][2] = W_fi[3 * rr + 2];
        bfe[1][g] = b_fi[rr] + gib[g * SZ + HF + j2]; }
    }
    float cpre[2][3];
#pragma unroll
    for (int u = 0; u < 2; ++u) {
      const int j = u ? j2 : j1;
      const size_t cbase = (((size_t)b * TT) * 3) * SZ + HF + j;
      cpre[u][0] = cond[cbase]; cpre[u][1] = cond[cbase + SZ]; cpre[u][2] = cond[cbase + 2 * SZ];
    }
    float cvO = -1.f, fvO = -1.f;
    const int ct = (tid < 112) ? tid : 111;

    for (int t = 0; t < TT; ++t) {
      const int q = t & 1;     // ch_t / fh_t buffer
      if (tid < NCWG) waitFlag(&g_cdone[tid * 16], (uint32_t)(t + 1));
      __syncthreads();
      // stage ch_t + prefetch hpf rows (one pipelined coherent block)
      f32x4 hpA, hpB;
      {
        const float* pch = g_hid + (size_t)q * BB * SZ + b * SZ + 4 * ct;
        const float* ph1 = g_hpf4 + ((size_t)j1 * 16 + b) * 4;
        const float* ph2 = g_hpf4 + ((size_t)j2 * 16 + b) * 4;
        f32x4 chv;
        cload3x4(pch, ph1, ph2, chv, hpA, hpB);
        if (tid < 112) *(f32x4*)&slds[4 * tid] = chv;
      }
      __syncthreads();
      logits256(g_wbct, b_bc, slds, llds, tid);
      __syncthreads();
      const uint2 kf = tf2(0u, 1u, 0u, (uint32_t)t);
      const uint2 kA = tf2(kf.x, kf.y, 0u, 0u);
      const uint2 kB = tf2(kf.x, kf.y, 0u, 1u);
      const int sc = sample256(llds, kA.x, kA.y, b, tid, redS, redI);
      const float cvNew = (float)sc / 127.5f - 1.0f;
      if (tid == 0) out[b * TT + t] = (float)sc;
      // fine gates (all local: hpA/hpB regs, flds LDS)
      {
        const float fp0 = fmaf(cvO, wf[0][0][0], fmaf(fvO, wf[0][0][1],
                           fmaf(cvNew, wf[0][0][2], bfe[0][0]))) + cpre[0][0];
        const float fp1 = fmaf(cvO, wf[0][1][0], fmaf(fvO, wf[0][1][1],
                           fmaf(cvNew, wf[0][1][2], bfe[0][1]))) + cpre[0][1];
        const float fp2 = fmaf(cvO, wf[0][2][0], fmaf(fvO, wf[0][2][1],
                           fmaf(cvNew, wf[0][2][2], bfe[0][2]))) + cpre[0][2];
        const float fhold = flds[j1];
        const float rg = 1.f / (1.f + expf(-(fp0 + hpA.x)));
        const float ug = 1.f / (1.f + expf(-(fp1 + hpA.y)));
        const float eg = tanhf(fmaf(rg, hpA.z, fp2));
        flds[j1] = ug * fhold + (1.f - ug) * eg;
      }
      if (has2) {
        const float fp0 = fmaf(cvO, wf[1][0][0], fmaf(fvO, wf[1][0][1],
                           fmaf(cvNew, wf[1][0][2], bfe[1][0]))) + cpre[1][0];
        const float fp1 = fmaf(cvO, wf[1][1][0], fmaf(fvO, wf[1][1][1],
                           fmaf(cvNew, wf[1][1][2], bfe[1][1]))) + cpre[1][1];
        const float fp2 = fmaf(cvO, wf[1][2][0], fmaf(fvO, wf[1][2][1],
                           fmaf(cvNew, wf[1][2][2], bfe[1][2]))) + cpre[1][2];
        const float fhold = flds[j2];
        const float rg = 1.f / (1.f + expf(-(fp0 + hpB.x)));
        const float ug = 1.f / (1.f + expf(-(fp1 + hpB.y)));
        const float eg = tanhf(fmaf(rg, hpB.z, fp2));
        flds[j2] = ug * fhold + (1.f - ug) * eg;
      }
      __syncthreads();
      // publish fh_t early (before fine logits) + flag A carrying sc
      if (tid < 224) {
        f32x2 f2; f2.x = flds[2 * tid]; f2.y = flds[2 * tid + 1];
        cstore2d(&g_hid[(size_t)q * BB * SZ + b * SZ + HF + 2 * tid], f2);
      }
      __syncthreads();
      if (tid == 0)
        __hip_atomic_store(&g_sdA[b * 16], ((uint32_t)(t + 1) << 8) | (uint32_t)sc,
                           __ATOMIC_RELAXED, __HIP_MEMORY_SCOPE_AGENT);
      logits256(g_wbft, b_bf, flds, llds, tid);
      __syncthreads();
      const int sf = sample256(llds, kB.x, kB.y, b, tid, redS, redI);
      const float fvNew = (float)sf / 127.5f - 1.0f;
      if (tid == 0) {
        out[BB * TT + b * TT + t] = (float)sf;
        __hip_atomic_store(&g_sdB[b * 16], ((uint32_t)(t + 1) << 8) | (uint32_t)sf,
                           __ATOMIC_RELAXED, __HIP_MEMORY_SCOPE_AGENT);
      }
      cvO = cvNew; fvO = fvNew;
      if (t + 1 < TT) {
#pragma unroll
        for (int u = 0; u < 2; ++u) {
          const int j = u ? j2 : j1;
          const size_t cbase = (((size_t)b * TT + (t + 1)) * 3) * SZ + HF + j;
          cpre[u][0] = cond[cbase]; cpre[u][1] = cond[cbase + SZ];
          cpre[u][2] = cond[cbase + 2 * SZ];
        }
      }
    }
    // final hidden: ch_999 in slds, fh_999 in flds
    for (int i = tid; i < SZ; i += 256)
      out[2 * BB * TT + (size_t)b * SZ + i] = (i < HF) ? slds[i] : flds[i - HF];
  }
}

extern "C" void kernel_launch(void* const* d_in, const int* in_sizes, int n_in,
                              void* d_out, int out_size, void* d_ws, size_t ws_size,
                              hipStream_t stream) {
  (void)in_sizes; (void)n_in; (void)out_size; (void)d_ws; (void)ws_size;
  const float* cond = (const float*)d_in[0];
  const float* gib  = (const float*)d_in[1];
  const float* W_h  = (const float*)d_in[2];
  const float* b_h  = (const float*)d_in[3];
  const float* W_ci = (const float*)d_in[4];
  const float* b_ci = (const float*)d_in[5];
  const float* W_fi = (const float*)d_in[6];
  const float* b_fi = (const float*)d_in[7];
  const float* W_bc = (const float*)d_in[8];
  const float* b_bc = (const float*)d_in[9];
  const float* W_bf = (const float*)d_in[10];
  const float* b_bf = (const float*)d_in[11];
  float* out = (float*)d_out;
  wavernn_init<<<448, 256, 0, stream>>>(W_bc, W_bf);
  wavernn_main<<<NWG, 256, 0, stream>>>(cond, gib, W_h, b_h, W_ci, b_ci,
                                        W_fi, b_fi, b_bc, b_bf, out);
}

// Round 5
// 22757.881 us; speedup vs baseline: 6.9322x; 1.4961x over previous
//
#include <hip/hip_runtime.h>
#include <stdint.h>

#define BB 16
#define TT 1000
#define SZ 896
#define HF 448
#define NCWG 224
#define NSWG 32            // 2 sampler WGs per batch
#define NWG  256

typedef float f32x4 __attribute__((ext_vector_type(4)));
typedef float f32x2 __attribute__((ext_vector_type(2)));

// Persistent device-global state.
__device__ float g_wbct[HF * 256];       // W_bc^T [448][256]
__device__ float g_wbft[HF * 256];       // W_bf^T [448][256]
__device__ float g_hid[2 * BB * SZ];     // double-buffered hidden [2][16][896]
__device__ float g_hpf4[HF * BB * 4];    // fine hp rows [448][16][4] = {h_r,h_u,h_e,pad}
__device__ uint32_t g_cdone[NCWG * 16];          // compute flags: value = t+1
__device__ uint32_t g_fhdone[NSWG * 16];         // sampler fh-published: ((t+1)<<8)|sc
__device__ unsigned long long g_afl[NSWG * 8];   // coarse argmax: hi=((t+1)<<16)|(bin<<8), lo=s bits
__device__ unsigned long long g_bfl[NSWG * 8];   // fine  argmax: same encoding

// ---- pipelined coherent (L2-bypassing) loads/stores ----
__device__ __forceinline__ void cload7x4(const float* p, f32x4& a0, f32x4& a1, f32x4& a2,
                                         f32x4& a3, f32x4& a4, f32x4& a5, f32x4& a6) {
  asm volatile(
      "global_load_dwordx4 %0, %7, off sc0 sc1\n\t"
      "global_load_dwordx4 %1, %7, off offset:16 sc0 sc1\n\t"
      "global_load_dwordx4 %2, %7, off offset:32 sc0 sc1\n\t"
      "global_load_dwordx4 %3, %7, off offset:48 sc0 sc1\n\t"
      "global_load_dwordx4 %4, %7, off offset:64 sc0 sc1\n\t"
      "global_load_dwordx4 %5, %7, off offset:80 sc0 sc1\n\t"
      "global_load_dwordx4 %6, %7, off offset:96 sc0 sc1\n\t"
      "s_waitcnt vmcnt(0)"
      : "=&v"(a0), "=&v"(a1), "=&v"(a2), "=&v"(a3), "=&v"(a4), "=&v"(a5), "=&v"(a6)
      : "v"(p) : "memory");
}
__device__ __forceinline__ void cload3x4(const float* p0, const float* p1, const float* p2,
                                         f32x4& a, f32x4& b, f32x4& c) {
  asm volatile(
      "global_load_dwordx4 %0, %3, off sc0 sc1\n\t"
      "global_load_dwordx4 %1, %4, off sc0 sc1\n\t"
      "global_load_dwordx4 %2, %5, off sc0 sc1\n\t"
      "s_waitcnt vmcnt(0)"
      : "=&v"(a), "=&v"(b), "=&v"(c)
      : "v"(p0), "v"(p1), "v"(p2) : "memory");
}
__device__ __forceinline__ void cstore1d(float* p, float v) {
  asm volatile("global_store_dword %0, %1, off sc0 sc1\n\ts_waitcnt vmcnt(0)"
               :: "v"(p), "v"(v) : "memory");
}
__device__ __forceinline__ void cstore2d(float* p, f32x2 v) {
  asm volatile("global_store_dwordx2 %0, %1, off sc0 sc1\n\ts_waitcnt vmcnt(0)"
               :: "v"(p), "v"(v) : "memory");
}
__device__ __forceinline__ void cstore4d(float* p, f32x4 v) {
  asm volatile("global_store_dwordx4 %0, %1, off sc0 sc1\n\ts_waitcnt vmcnt(0)"
               :: "v"(p), "v"(v) : "memory");
}
// fire-and-forget flag stores (no drain needed; data stores were drained pre-barrier)
__device__ __forceinline__ void cstore1u_nw(uint32_t* p, uint32_t v) {
  asm volatile("global_store_dword %0, %1, off sc0 sc1" :: "v"(p), "v"(v) : "memory");
}
__device__ __forceinline__ void cstore2u_nw(unsigned long long* p, f32x2 v) {
  asm volatile("global_store_dwordx2 %0, %1, off sc0 sc1" :: "v"(p), "v"(v) : "memory");
}

__device__ __forceinline__ void waitFlag(uint32_t* f, uint32_t target) {
  while (__hip_atomic_load(f, __ATOMIC_RELAXED, __HIP_MEMORY_SCOPE_AGENT) < target)
    __builtin_amdgcn_s_sleep(1);
}
__device__ __forceinline__ void waitFlagA(uint32_t* f, uint32_t target) {
  while (__hip_atomic_load(f, __ATOMIC_RELAXED, __HIP_MEMORY_SCOPE_AGENT) < target)
    __builtin_amdgcn_s_sleep(4);
}
__device__ __forceinline__ unsigned long long waitFlag64(unsigned long long* f, uint32_t tag) {
  unsigned long long u;
  while ((uint32_t)((u = __hip_atomic_load(f, __ATOMIC_RELAXED, __HIP_MEMORY_SCOPE_AGENT)) >> 48) < tag)
    __builtin_amdgcn_s_sleep(1);
  return u;
}
__device__ __forceinline__ uint32_t waitFlagHi8(uint32_t* f, uint32_t tag) {
  uint32_t v;
  while (((v = __hip_atomic_load(f, __ATOMIC_RELAXED, __HIP_MEMORY_SCOPE_AGENT)) >> 8) < tag)
    __builtin_amdgcn_s_sleep(1);
  return v;
}

__device__ __forceinline__ uint32_t rotl32(uint32_t v, int d) {
  return (v << d) | (v >> (32 - d));
}

// JAX threefry2x32 (20 rounds), bit-exact
__device__ __forceinline__ uint2 tf2(uint32_t k0, uint32_t k1, uint32_t x0, uint32_t x1) {
  const uint32_t k2 = k0 ^ k1 ^ 0x1BD11BDAu;
  x0 += k0; x1 += k1;
  x0 += x1; x1 = rotl32(x1,13); x1 ^= x0;
  x0 += x1; x1 = rotl32(x1,15); x1 ^= x0;
  x0 += x1; x1 = rotl32(x1,26); x1 ^= x0;
  x0 += x1; x1 = rotl32(x1, 6); x1 ^= x0;
  x0 += k1; x1 += k2 + 1u;
  x0 += x1; x1 = rotl32(x1,17); x1 ^= x0;
  x0 += x1; x1 = rotl32(x1,29); x1 ^= x0;
  x0 += x1; x1 = rotl32(x1,16); x1 ^= x0;
  x0 += x1; x1 = rotl32(x1,24); x1 ^= x0;
  x0 += k2; x1 += k0 + 2u;
  x0 += x1; x1 = rotl32(x1,13); x1 ^= x0;
  x0 += x1; x1 = rotl32(x1,15); x1 ^= x0;
  x0 += x1; x1 = rotl32(x1,26); x1 ^= x0;
  x0 += x1; x1 = rotl32(x1, 6); x1 ^= x0;
  x0 += k0; x1 += k1 + 3u;
  x0 += x1; x1 = rotl32(x1,17); x1 ^= x0;
  x0 += x1; x1 = rotl32(x1,29); x1 ^= x0;
  x0 += x1; x1 = rotl32(x1,16); x1 ^= x0;
  x0 += x1; x1 = rotl32(x1,24); x1 ^= x0;
  x0 += k1; x1 += k2 + 4u;
  x0 += x1; x1 = rotl32(x1,13); x1 ^= x0;
  x0 += x1; x1 = rotl32(x1,15); x1 ^= x0;
  x0 += x1; x1 = rotl32(x1,26); x1 ^= x0;
  x0 += x1; x1 = rotl32(x1, 6); x1 ^= x0;
  x0 += k2; x1 += k0 + 5u;
  return make_uint2(x0, x1);
}

__device__ __forceinline__ float gumbel_bits(uint32_t bits) {
  const float tiny = 1.17549435e-38f;
  float f = __uint_as_float((bits >> 9) | 0x3f800000u) - 1.0f;
  float u = fmaxf(tiny, f + tiny);
  return -logf(-logf(u));
}

// 128-bin logit slice: 32 groups of 4 bins x 8 K-threads (56-elem chains)
__device__ __forceinline__ void logits128(const float* __restrict__ WT,
                                          const float* __restrict__ bias,
                                          const float* __restrict__ vec,
                                          float* __restrict__ llds, int tid, int k) {
  const int g = tid >> 3, kth = tid & 7;
  const int nb = k * 128 + 4 * g;
  float ax = 0.f, ay = 0.f, az = 0.f, aw = 0.f;
  const float* wp = WT + (size_t)(kth * 56) * 256 + nb;
  const float* cp = vec + kth * 56;
#pragma unroll 8
  for (int ii = 0; ii < 56; ++ii) {
    const float c = cp[ii];
    const float4 w4 = *(const float4*)(wp + (size_t)ii * 256);
    ax = fmaf(c, w4.x, ax); ay = fmaf(c, w4.y, ay);
    az = fmaf(c, w4.z, az); aw = fmaf(c, w4.w, aw);
  }
  ax += __shfl_xor(ax, 1); ax += __shfl_xor(ax, 2); ax += __shfl_xor(ax, 4);
  ay += __shfl_xor(ay, 1); ay += __shfl_xor(ay, 2); ay += __shfl_xor(ay, 4);
  az += __shfl_xor(az, 1); az += __shfl_xor(az, 2); az += __shfl_xor(az, 4);
  aw += __shfl_xor(aw, 1); aw += __shfl_xor(aw, 2); aw += __shfl_xor(aw, 4);
  if (kth == 0) {
    llds[4 * g + 0] = ax + bias[nb + 0];
    llds[4 * g + 1] = ay + bias[nb + 1];
    llds[4 * g + 2] = az + bias[nb + 2];
    llds[4 * g + 3] = aw + bias[nb + 3];
  }
}

__global__ __launch_bounds__(256, 1) void wavernn_init(const float* __restrict__ W_bc,
                                                       const float* __restrict__ W_bf) {
  const int idx = blockIdx.x * 256 + threadIdx.x;   // grid 448*256 = 114688
  const int ich = idx >> 8, n = idx & 255;
  g_wbct[idx] = W_bc[n * HF + ich];
  g_wbft[idx] = W_bf[n * HF + ich];
  if (idx < 2 * BB * SZ) g_hid[idx] = 0.f;
  if (idx < NCWG * 16) g_cdone[idx] = 0u;
  if (idx < NSWG * 16) g_fhdone[idx] = 0u;
  if (idx < NSWG * 8) { g_afl[idx] = 0ull; g_bfl[idx] = 0ull; }
}

__global__ __launch_bounds__(256, 1) void wavernn_main(
    const float* __restrict__ cond, const float* __restrict__ gib,
    const float* __restrict__ W_h,  const float* __restrict__ b_h,
    const float* __restrict__ W_ci, const float* __restrict__ b_ci,
    const float* __restrict__ W_fi, const float* __restrict__ b_fi,
    const float* __restrict__ b_bc, const float* __restrict__ b_bf,
    float* __restrict__ out) {
  __shared__ float hlds[14400];
  __shared__ int smcv[16], smfv[16];
  const int wg = blockIdx.x, tid = threadIdx.x;

  if (wg < NCWG) {
    // ================= compute role (unchanged math) =================
    const int wave = tid >> 6, lane = tid & 63;
    const int l32 = lane >> 1, b2 = lane & 1;
    const bool isC = wave < 2;
    const int chan = (wg << 1) | (wave & 1);           // 0..447
    const int rb = isC ? chan : (HF + chan);
    float4 w[3][7];
    float brow[3];
#pragma unroll
    for (int r = 0; r < 3; ++r) {
      const int row = r * SZ + rb;
      brow[r] = b_h[row];
#pragma unroll
      for (int m = 0; m < 7; ++m)
        w[r][m] = *(const float4*)&W_h[(size_t)row * SZ + 4 * l32 + 128 * m];
    }
    float wci0[3], wci1[3], bcie[3];
    if (isC) {
#pragma unroll
      for (int g = 0; g < 3; ++g) {
        const int rr = g * HF + chan;
        wci0[g] = W_ci[2 * rr]; wci1[g] = W_ci[2 * rr + 1];
        bcie[g] = b_ci[rr] + gib[g * SZ + chan];
      }
    }
    float pc0 = 0.f, pc1 = 0.f, pc2 = 0.f;
    if (isC && lane < 16) {
      const size_t base = (((size_t)lane * TT) * 3) * SZ + chan;
      pc0 = cond[base]; pc1 = cond[base + SZ]; pc2 = cond[base + 2 * SZ];
    }
    float chreg = 0.f;
    const int sb = tid >> 4, sl = tid & 15;

    for (int t = 0; t < TT; ++t) {
      const int p = (t & 1) ^ 1;   // hidden_{t-1}
      const int q = t & 1;         // ch_t / hpf_t destination
      // ---- Phase A: all compute WGs published ch_{t-1}; stage coarse half, partial matvec
      if (tid < NCWG) waitFlagA(&g_cdone[tid * 16], (uint32_t)t);
      __syncthreads();
      {
        const float* src = g_hid + (size_t)p * BB * SZ + sb * SZ + 28 * sl;
        f32x4 a0, a1, a2, a3, a4, a5, a6;
        cload7x4(src, a0, a1, a2, a3, a4, a5, a6);
        float* dst = hlds + sb * 900 + 28 * sl;
        *(f32x4*)(dst)      = a0; *(f32x4*)(dst + 4)  = a1;
        *(f32x4*)(dst + 8)  = a2; *(f32x4*)(dst + 12) = a3;
        *(f32x4*)(dst + 16) = a4; *(f32x4*)(dst + 20) = a5;
        *(f32x4*)(dst + 24) = a6;
      }
      __syncthreads();
      float acc[3][8];
#pragma unroll
      for (int r = 0; r < 3; ++r)
#pragma unroll
        for (int i = 0; i < 8; ++i) acc[r][i] = 0.f;
#pragma unroll
      for (int i = 0; i < 8; ++i) {
        const int b = b2 + 2 * i;
        const float* hb = hlds + b * 900 + 4 * l32;
        const float4 h0 = *(const float4*)(hb);
        const float4 h1 = *(const float4*)(hb + 128);
        const float4 h2 = *(const float4*)(hb + 256);
#pragma unroll
        for (int r = 0; r < 3; ++r) {
          float s = acc[r][i];
          s = fmaf(w[r][0].x, h0.x, s); s = fmaf(w[r][0].y, h0.y, s);
          s = fmaf(w[r][0].z, h0.z, s); s = fmaf(w[r][0].w, h0.w, s);
          s = fmaf(w[r][1].x, h1.x, s); s = fmaf(w[r][1].y, h1.y, s);
          s = fmaf(w[r][1].z, h1.z, s); s = fmaf(w[r][1].w, h1.w, s);
          s = fmaf(w[r][2].x, h2.x, s); s = fmaf(w[r][2].y, h2.y, s);
          s = fmaf(w[r][2].z, h2.z, s); s = fmaf(w[r][2].w, h2.w, s);
          acc[r][i] = s;
        }
        if (l32 < 16) {
          const float4 h3 = *(const float4*)(hb + 384);
#pragma unroll
          for (int r = 0; r < 3; ++r) {
            float s = acc[r][i];
            s = fmaf(w[r][3].x, h3.x, s); s = fmaf(w[r][3].y, h3.y, s);
            s = fmaf(w[r][3].z, h3.z, s); s = fmaf(w[r][3].w, h3.w, s);
            acc[r][i] = s;
          }
        }
      }
      // ---- Phase B1: fh_{t-1} published (fhdone >= t); also deliver sc_{t-1}
      if (tid < NSWG) {
        const uint32_t v = waitFlagHi8(&g_fhdone[tid * 16], (uint32_t)t);
        if (!(tid & 1)) smcv[tid >> 1] = (int)(v & 255u);
      }
      __syncthreads();
      {
        const float* src = g_hid + (size_t)p * BB * SZ + sb * SZ + HF + 28 * sl;
        f32x4 a0, a1, a2, a3, a4, a5, a6;
        cload7x4(src, a0, a1, a2, a3, a4, a5, a6);
        float* dst = hlds + sb * 900 + HF + 28 * sl;
        *(f32x4*)(dst)      = a0; *(f32x4*)(dst + 4)  = a1;
        *(f32x4*)(dst + 8)  = a2; *(f32x4*)(dst + 12) = a3;
        *(f32x4*)(dst + 16) = a4; *(f32x4*)(dst + 20) = a5;
        *(f32x4*)(dst + 24) = a6;
      }
      __syncthreads();
#pragma unroll
      for (int i = 0; i < 8; ++i) {
        const int b = b2 + 2 * i;
        const float* hb = hlds + b * 900 + 4 * l32;
        if (l32 >= 16) {
          const float4 h3 = *(const float4*)(hb + 384);
#pragma unroll
          for (int r = 0; r < 3; ++r) {
            float s = acc[r][i];
            s = fmaf(w[r][3].x, h3.x, s); s = fmaf(w[r][3].y, h3.y, s);
            s = fmaf(w[r][3].z, h3.z, s); s = fmaf(w[r][3].w, h3.w, s);
            acc[r][i] = s;
          }
        }
        const float4 h4 = *(const float4*)(hb + 512);
        const float4 h5 = *(const float4*)(hb + 640);
        const float4 h6 = *(const float4*)(hb + 768);
#pragma unroll
        for (int r = 0; r < 3; ++r) {
          float s = acc[r][i];
          s = fmaf(w[r][4].x, h4.x, s); s = fmaf(w[r][4].y, h4.y, s);
          s = fmaf(w[r][4].z, h4.z, s); s = fmaf(w[r][4].w, h4.w, s);
          s = fmaf(w[r][5].x, h5.x, s); s = fmaf(w[r][5].y, h5.y, s);
          s = fmaf(w[r][5].z, h5.z, s); s = fmaf(w[r][5].w, h5.w, s);
          s = fmaf(w[r][6].x, h6.x, s); s = fmaf(w[r][6].y, h6.y, s);
          s = fmaf(w[r][6].z, h6.z, s); s = fmaf(w[r][6].w, h6.w, s);
          acc[r][i] = s;
        }
      }
#pragma unroll
      for (int r = 0; r < 3; ++r)
#pragma unroll
        for (int i = 0; i < 8; ++i) {
          float v = acc[r][i];
          v += __shfl_xor(v, 2);
          v += __shfl_xor(v, 4);
          v += __shfl_xor(v, 8);
          v += __shfl_xor(v, 16);
          v += __shfl_xor(v, 32);
          acc[r][i] = v;
        }
      // ---- Phase B2: sf_{t-1} from B-flags (pairwise combine)
      if (tid < NSWG) {
        const unsigned long long u = waitFlag64(&g_bfl[tid * 8], (uint32_t)t);
        float s = __uint_as_float((uint32_t)u);
        int bin = (int)((u >> 40) & 255u);
        const float so = __shfl_xor(s, 1);
        const int bino = __shfl_xor(bin, 1);
        if (so > s || (so == s && bino < bin)) bin = bino;
        if (!(tid & 1)) smfv[tid >> 1] = bin;
      }
      __syncthreads();
      if (lane < 16) {
        const int bb = lane, i = lane >> 1;
        const float s0 = acc[0][i] + brow[0];
        const float s1 = acc[1][i] + brow[1];
        const float s2 = acc[2][i] + brow[2];
        if (isC) {
          const float cvv = (float)smcv[bb] / 127.5f - 1.0f;
          const float fvv = (float)smfv[bb] / 127.5f - 1.0f;
          const float cp0 = fmaf(cvv, wci0[0], fmaf(fvv, wci1[0], bcie[0])) + pc0;
          const float cp1 = fmaf(cvv, wci0[1], fmaf(fvv, wci1[1], bcie[1])) + pc1;
          const float cp2 = fmaf(cvv, wci0[2], fmaf(fvv, wci1[2], bcie[2])) + pc2;
          const float rg = 1.f / (1.f + expf(-(cp0 + s0)));
          const float ug = 1.f / (1.f + expf(-(cp1 + s1)));
          const float eg = tanhf(fmaf(rg, s2, cp2));
          const float chn = ug * chreg + (1.f - ug) * eg;
          chreg = chn;
          cstore1d(&g_hid[(size_t)q * BB * SZ + bb * SZ + chan], chn);
        } else {
          f32x4 hv; hv.x = s0; hv.y = s1; hv.z = s2; hv.w = 0.f;
          cstore4d(&g_hpf4[((size_t)chan * 16 + bb) * 4], hv);
        }
      }
      __syncthreads();
      if (tid == 0) cstore1u_nw(&g_cdone[wg * 16], (uint32_t)(t + 1));
      if (isC && lane < 16 && t + 1 < TT) {
        const size_t base = (((size_t)lane * TT + (t + 1)) * 3) * SZ + chan;
        pc0 = cond[base]; pc1 = cond[base + SZ]; pc2 = cond[base + 2 * SZ];
      }
    }
  } else {
    // ================= sampler role: 2 WGs per batch, 128 bins each ==========
    const int swg = wg - NCWG;          // 0..31
    const int b = swg >> 1, k = swg & 1;
    float* slds = hlds;                 // [448] ch_t
    float* flds = hlds + 448;           // [448] fh persistent
    float* llds = hlds + 896;           // [128] local logit bins
    float* redS = hlds + 1024;          // [4]
    int*   redI = (int*)(hlds + 1028);  // [4]
    const int j1 = tid;
    const bool has2 = (tid + 256 < HF); // tid < 192
    const int j2 = has2 ? (tid + 256) : (HF - 1);
    if (tid < 224) { flds[tid] = 0.f; flds[tid + 224] = 0.f; }
    float wf[2][3][3], bfe[2][3];
#pragma unroll
    for (int g = 0; g < 3; ++g) {
      { const int rr = g * HF + j1;
        wf[0][g][0] = W_fi[3 * rr]; wf[0][g][1] = W_fi[3 * rr + 1]; wf[0][g][2] = W_fi[3 * rr + 2];
        bfe[0][g] = b_fi[rr] + gib[g * SZ + HF + j1]; }
      { const int rr = g * HF + j2;
        wf[1][g][0] = W_fi[3 * rr]; wf[1][g][1] = W_fi[3 * rr + 1]; wf[1][g][2] = W_fi[3 * rr + 2];
        bfe[1][g] = b_fi[rr] + gib[g * SZ + HF + j2]; }
    }
    float cpre[2][3];
#pragma unroll
    for (int u = 0; u < 2; ++u) {
      const int j = u ? j2 : j1;
      const size_t cbase = (((size_t)b * TT) * 3) * SZ + HF + j;
      cpre[u][0] = cond[cbase]; cpre[u][1] = cond[cbase + SZ]; cpre[u][2] = cond[cbase + 2 * SZ];
    }
    float cvO = -1.f, fvO = -1.f;
    const int ct = (tid < 112) ? tid : 0;
    unsigned long long* aflP = &g_afl[(swg ^ 1) * 8];
    unsigned long long* bflP = &g_bfl[(swg ^ 1) * 8];

    for (int t = 0; t < TT; ++t) {
      const int q = t & 1;
      if (tid < NCWG) waitFlag(&g_cdone[tid * 16], (uint32_t)(t + 1));
      __syncthreads();
      // stage ch_t (tid<112) + hpf rows for this thread's gate channels
      f32x4 hpA, hpB;
      {
        const float* pch = g_hid + (size_t)q * BB * SZ + b * SZ + 4 * ct;
        const float* ph1 = g_hpf4 + ((size_t)j1 * 16 + b) * 4;
        const float* ph2 = g_hpf4 + ((size_t)j2 * 16 + b) * 4;
        f32x4 chv;
        cload3x4(pch, ph1, ph2, chv, hpA, hpB);
        if (tid < 112) *(f32x4*)&slds[4 * tid] = chv;
      }
      __syncthreads();
      // coarse logits (own 128 bins)
      logits256:;
      logits128(g_wbct, b_bc, slds, llds, tid, k);
      __syncthreads();
      const uint2 kf = tf2(0u, 1u, 0u, (uint32_t)t);
      const uint2 kA = tf2(kf.x, kf.y, 0u, 0u);
      const uint2 kB = tf2(kf.x, kf.y, 0u, 1u);
      // local argmax over own 128 bins (+gumbel)
      float sL = 0.f; int nL = 0;
      if (tid < 128) {
        const int n = k * 128 + tid;
        const uint2 o = tf2(kA.x, kA.y, 0u, (uint32_t)(b * 256 + n));
        float s = llds[tid] + gumbel_bits(o.x ^ o.y);
        int idx = n;
#pragma unroll
        for (int mask = 1; mask < 64; mask <<= 1) {
          const float so = __shfl_xor(s, mask);
          const int io = __shfl_xor(idx, mask);
          if (so > s || (so == s && io < idx)) { s = so; idx = io; }
        }
        if ((tid & 63) == 0) { redS[tid >> 6] = s; redI[tid >> 6] = idx; }
      }
      __syncthreads();
      {
        float s0 = redS[0]; int n0 = redI[0];
        const float s1 = redS[1]; const int n1 = redI[1];
        if (s1 > s0 || (s1 == s0 && n1 < n0)) { s0 = s1; n0 = n1; }
        sL = s0; nL = n0;
      }
      // exchange with partner WG -> sc
      if (tid == 0) {
        f32x2 v; v.x = sL;
        v.y = __uint_as_float(((uint32_t)(t + 1) << 16) | ((uint32_t)nL << 8));
        cstore2u_nw(&g_afl[swg * 8], v);
      }
      if (tid == 64) {
        const unsigned long long u = waitFlag64(aflP, (uint32_t)(t + 1));
        redS[2] = __uint_as_float((uint32_t)u);
        redI[2] = (int)((u >> 40) & 255u);
      }
      __syncthreads();
      int sc = nL;
      { const float sP = redS[2]; const int nP = redI[2];
        if (sP > sL || (sP == sL && nP < nL)) sc = nP; }
      const float cvNew = (float)sc / 127.5f - 1.0f;
      if (k == 0 && tid == 0) out[b * TT + t] = (float)sc;
      // fine gates (redundant: full 448)
      {
        const float fp0 = fmaf(cvO, wf[0][0][0], fmaf(fvO, wf[0][0][1],
                           fmaf(cvNew, wf[0][0][2], bfe[0][0]))) + cpre[0][0];
        const float fp1 = fmaf(cvO, wf[0][1][0], fmaf(fvO, wf[0][1][1],
                           fmaf(cvNew, wf[0][1][2], bfe[0][1]))) + cpre[0][1];
        const float fp2 = fmaf(cvO, wf[0][2][0], fmaf(fvO, wf[0][2][1],
                           fmaf(cvNew, wf[0][2][2], bfe[0][2]))) + cpre[0][2];
        const float fhold = flds[j1];
        const float rg = 1.f / (1.f + expf(-(fp0 + hpA.x)));
        const float ug = 1.f / (1.f + expf(-(fp1 + hpA.y)));
        const float eg = tanhf(fmaf(rg, hpA.z, fp2));
        flds[j1] = ug * fhold + (1.f - ug) * eg;
      }
      if (has2) {
        const float fp0 = fmaf(cvO, wf[1][0][0], fmaf(fvO, wf[1][0][1],
                           fmaf(cvNew, wf[1][0][2], bfe[1][0]))) + cpre[1][0];
        const float fp1 = fmaf(cvO, wf[1][1][0], fmaf(fvO, wf[1][1][1],
                           fmaf(cvNew, wf[1][1][2], bfe[1][1]))) + cpre[1][1];
        const float fp2 = fmaf(cvO, wf[1][2][0], fmaf(fvO, wf[1][2][1],
                           fmaf(cvNew, wf[1][2][2], bfe[1][2]))) + cpre[1][2];
        const float fhold = flds[j2];
        const float rg = 1.f / (1.f + expf(-(fp0 + hpB.x)));
        const float ug = 1.f / (1.f + expf(-(fp1 + hpB.y)));
        const float eg = tanhf(fmaf(rg, hpB.z, fp2));
        flds[j2] = ug * fhold + (1.f - ug) * eg;
      }
      __syncthreads();
      // publish own fh half-slice [224k, 224k+224)
      if (tid < 112) {
        const int idx = 224 * k + 2 * tid;
        f32x2 v; v.x = flds[idx]; v.y = flds[idx + 1];
        cstore2d(&g_hid[(size_t)q * BB * SZ + b * SZ + HF + idx], v);
      }
      __syncthreads();
      if (tid == 0)
        cstore1u_nw(&g_fhdone[swg * 16], ((uint32_t)(t + 1) << 8) | (uint32_t)sc);
      // fine logits
      logits128(g_wbft, b_bf, flds, llds, tid, k);
      __syncthreads();
      float sLf = 0.f; int nLf = 0;
      if (tid < 128) {
        const int n = k * 128 + tid;
        const uint2 o = tf2(kB.x, kB.y, 0u, (uint32_t)(b * 256 + n));
        float s = llds[tid] + gumbel_bits(o.x ^ o.y);
        int idx = n;
#pragma unroll
        for (int mask = 1; mask < 64; mask <<= 1) {
          const float so = __shfl_xor(s, mask);
          const int io = __shfl_xor(idx, mask);
          if (so > s || (so == s && io < idx)) { s = so; idx = io; }
        }
        if ((tid & 63) == 0) { redS[tid >> 6] = s; redI[tid >> 6] = idx; }
      }
      __syncthreads();
      {
        float s0 = redS[0]; int n0 = redI[0];
        const float s1 = redS[1]; const int n1 = redI[1];
        if (s1 > s0 || (s1 == s0 && n1 < n0)) { s0 = s1; n0 = n1; }
        sLf = s0; nLf = n0;
      }
      if (tid == 0) {
        f32x2 v; v.x = sLf;
        v.y = __uint_as_float(((uint32_t)(t + 1) << 16) | ((uint32_t)nLf << 8));
        cstore2u_nw(&g_bfl[swg * 8], v);
      }
      if (tid == 64) {
        const unsigned long long u = waitFlag64(bflP, (uint32_t)(t + 1));
        redS[2] = __uint_as_float((uint32_t)u);
        redI[2] = (int)((u >> 40) & 255u);
      }
      __syncthreads();
      int sf = nLf;
      { const float sP = redS[2]; const int nP = redI[2];
        if (sP > sLf || (sP == sLf && nP < nLf)) sf = nP; }
      if (k == 0 && tid == 0) out[BB * TT + b * TT + t] = (float)sf;
      cvO = cvNew; fvO = (float)sf / 127.5f - 1.0f;
      if (t + 1 < TT) {
#pragma unroll
        for (int u = 0; u < 2; ++u) {
          const int j = u ? j2 : j1;
          const size_t cbase = (((size_t)b * TT + (t + 1)) * 3) * SZ + HF + j;
          cpre[u][0] = cond[cbase]; cpre[u][1] = cond[cbase + SZ];
          cpre[u][2] = cond[cbase + 2 * SZ];
        }
      }
    }
    // final hidden (k==0 WG writes): ch_999 in slds, fh_999 in flds
    if (k == 0)
      for (int i = tid; i < SZ; i += 256)
        out[2 * BB * TT + (size_t)b * SZ + i] = (i < HF) ? slds[i] : flds[i - HF];
  }
}

extern "C" void kernel_launch(void* const* d_in, const int* in_sizes, int n_in,
                              void* d_out, int out_size, void* d_ws, size_t ws_size,
                              hipStream_t stream) {
  (void)in_sizes; (void)n_in; (void)out_size; (void)d_ws; (void)ws_size;
  const float* cond = (const float*)d_in[0];
  const float* gib  = (const float*)d_in[1];
  const float* W_h  = (const float*)d_in[2];
  const float* b_h  = (const float*)d_in[3];
  const float* W_ci = (const float*)d_in[4];
  const float* b_ci = (const float*)d_in[5];
  const float* W_fi = (const float*)d_in[6];
  const float* b_fi = (const float*)d_in[7];
  const float* W_bc = (const float*)d_in[8];
  const float* b_bc = (const float*)d_in[9];
  const float* W_bf = (const float*)d_in[10];
  const float* b_bf = (const float*)d_in[11];
  float* out = (float*)d_out;
  wavernn_init<<<448, 256, 0, stream>>>(W_bc, W_bf);
  wavernn_main<<<NWG, 256, 0, stream>>>(cond, gib, W_h, b_h, W_ci, b_ci,
                                        W_fi, b_fi, b_bc, b_bf, out);
}

// Round 6
// 12152.310 us; speedup vs baseline: 12.9821x; 1.8727x over previous
//
#include <hip/hip_runtime.h>
#include <stdint.h>

#define BB 16
#define TT 1000
#define SZ 896
#define HF 448
#define NC 112            // compute WGs (4 channels each, 8 waves of 1 task)
#define NWG 240           // 112 compute + 128 sampler (16 batches x (4 coarse + 4 fine))
#define LDS_FLOATS 30112
#define LDS_BYTES (LDS_FLOATS * 4)

typedef float f32x4 __attribute__((ext_vector_type(4)));
typedef float f32x2 __attribute__((ext_vector_type(2)));

// Persistent device-global state.
__device__ float g_hid[2 * BB * SZ];     // double-buffered hidden [2][16][896]
__device__ float g_hpf4[HF * BB * 4];    // fine hp rows [448][16][4] = {h_r,h_u,h_e,pad}
__device__ uint32_t g_cdone[NC * 16];    // compute flags: value = t+1
__device__ uint32_t g_fhd[BB * 16];      // F0 fh published: ((t+1)<<8)|sc
__device__ uint32_t g_sfd[BB * 16];      // F0 fine sample: ((t+1)<<8)|sf
__device__ unsigned long long g_afl[BB * 4 * 8];  // coarse candidates {score, (t+1)<<16|bin<<8}
__device__ unsigned long long g_bfl[BB * 4 * 8];  // fine candidates

// ---- pipelined coherent (L2-bypassing) loads/stores ----
__device__ __forceinline__ void cload4x4(const float* p, f32x4& a0, f32x4& a1, f32x4& a2, f32x4& a3) {
  asm volatile(
      "global_load_dwordx4 %0, %4, off sc0 sc1\n\t"
      "global_load_dwordx4 %1, %4, off offset:16 sc0 sc1\n\t"
      "global_load_dwordx4 %2, %4, off offset:32 sc0 sc1\n\t"
      "global_load_dwordx4 %3, %4, off offset:48 sc0 sc1\n\t"
      "s_waitcnt vmcnt(0)"
      : "=&v"(a0), "=&v"(a1), "=&v"(a2), "=&v"(a3) : "v"(p) : "memory");
}
__device__ __forceinline__ f32x4 cload1x4(const float* p) {
  f32x4 a;
  asm volatile("global_load_dwordx4 %0, %1, off sc0 sc1\n\ts_waitcnt vmcnt(0)"
               : "=&v"(a) : "v"(p) : "memory");
  return a;
}
__device__ __forceinline__ void cstore1d(float* p, float v) {
  asm volatile("global_store_dword %0, %1, off sc0 sc1\n\ts_waitcnt vmcnt(0)"
               :: "v"(p), "v"(v) : "memory");
}
__device__ __forceinline__ void cstore4d(float* p, f32x4 v) {
  asm volatile("global_store_dwordx4 %0, %1, off sc0 sc1\n\ts_waitcnt vmcnt(0)"
               :: "v"(p), "v"(v) : "memory");
}
__device__ __forceinline__ void cstore1u_nw(uint32_t* p, uint32_t v) {
  asm volatile("global_store_dword %0, %1, off sc0 sc1" :: "v"(p), "v"(v) : "memory");
}
__device__ __forceinline__ void cstore2u_nw(unsigned long long* p, f32x2 v) {
  asm volatile("global_store_dwordx2 %0, %1, off sc0 sc1" :: "v"(p), "v"(v) : "memory");
}

__device__ __forceinline__ void waitFlag(uint32_t* f, uint32_t target) {
  while (__hip_atomic_load(f, __ATOMIC_RELAXED, __HIP_MEMORY_SCOPE_AGENT) < target)
    __builtin_amdgcn_s_sleep(1);
}
__device__ __forceinline__ void waitFlagA(uint32_t* f, uint32_t target) {
  while (__hip_atomic_load(f, __ATOMIC_RELAXED, __HIP_MEMORY_SCOPE_AGENT) < target)
    __builtin_amdgcn_s_sleep(2);
}
__device__ __forceinline__ unsigned long long waitFlag64(unsigned long long* f, uint32_t tag) {
  unsigned long long u;
  while ((uint32_t)((u = __hip_atomic_load(f, __ATOMIC_RELAXED, __HIP_MEMORY_SCOPE_AGENT)) >> 48) < tag)
    __builtin_amdgcn_s_sleep(1);
  return u;
}
__device__ __forceinline__ uint32_t waitFlagHi8(uint32_t* f, uint32_t tag) {
  uint32_t v;
  while (((v = __hip_atomic_load(f, __ATOMIC_RELAXED, __HIP_MEMORY_SCOPE_AGENT)) >> 8) < tag)
    __builtin_amdgcn_s_sleep(1);
  return v;
}

__device__ __forceinline__ uint32_t rotl32(uint32_t v, int d) {
  return (v << d) | (v >> (32 - d));
}

// JAX threefry2x32 (20 rounds), bit-exact
__device__ __forceinline__ uint2 tf2(uint32_t k0, uint32_t k1, uint32_t x0, uint32_t x1) {
  const uint32_t k2 = k0 ^ k1 ^ 0x1BD11BDAu;
  x0 += k0; x1 += k1;
  x0 += x1; x1 = rotl32(x1,13); x1 ^= x0;
  x0 += x1; x1 = rotl32(x1,15); x1 ^= x0;
  x0 += x1; x1 = rotl32(x1,26); x1 ^= x0;
  x0 += x1; x1 = rotl32(x1, 6); x1 ^= x0;
  x0 += k1; x1 += k2 + 1u;
  x0 += x1; x1 = rotl32(x1,17); x1 ^= x0;
  x0 += x1; x1 = rotl32(x1,29); x1 ^= x0;
  x0 += x1; x1 = rotl32(x1,16); x1 ^= x0;
  x0 += x1; x1 = rotl32(x1,24); x1 ^= x0;
  x0 += k2; x1 += k0 + 2u;
  x0 += x1; x1 = rotl32(x1,13); x1 ^= x0;
  x0 += x1; x1 = rotl32(x1,15); x1 ^= x0;
  x0 += x1; x1 = rotl32(x1,26); x1 ^= x0;
  x0 += x1; x1 = rotl32(x1, 6); x1 ^= x0;
  x0 += k0; x1 += k1 + 3u;
  x0 += x1; x1 = rotl32(x1,17); x1 ^= x0;
  x0 += x1; x1 = rotl32(x1,29); x1 ^= x0;
  x0 += x1; x1 = rotl32(x1,16); x1 ^= x0;
  x0 += x1; x1 = rotl32(x1,24); x1 ^= x0;
  x0 += k1; x1 += k2 + 4u;
  x0 += x1; x1 = rotl32(x1,13); x1 ^= x0;
  x0 += x1; x1 = rotl32(x1,15); x1 ^= x0;
  x0 += x1; x1 = rotl32(x1,26); x1 ^= x0;
  x0 += x1; x1 = rotl32(x1, 6); x1 ^= x0;
  x0 += k2; x1 += k0 + 5u;
  return make_uint2(x0, x1);
}

__device__ __forceinline__ float gumbel_bits(uint32_t bits) {
  const float tiny = 1.17549435e-38f;
  float f = __uint_as_float((bits >> 9) | 0x3f800000u) - 1.0f;
  float u = fmaxf(tiny, f + tiny);
  return -logf(-logf(u));
}

// 64-bin logit partials from LDS-resident weight slice wlds[448][65] (padded).
// Wave w covers K in [56w, 56w+56); lane = local bin. Bit-identical chain order to R5.
__device__ __forceinline__ void logits64(const float* __restrict__ wlds,
                                         const float* __restrict__ vec,
                                         float* __restrict__ plds, int tid) {
  const int w = tid >> 6, lane = tid & 63;
  float a = 0.f;
  const float* wp = wlds + (56 * w) * 65 + lane;
  const float* cp = vec + 56 * w;
#pragma unroll 8
  for (int ii = 0; ii < 56; ++ii)
    a = fmaf(cp[ii], wp[ii * 65], a);
  plds[(w << 6) | lane] = a;
}

__global__ __launch_bounds__(256, 1) void wavernn_init() {
  const int idx = blockIdx.x * 256 + threadIdx.x;   // 112 x 256 = 28672
  g_hid[idx] = 0.f;
  if (idx < NC * 16) g_cdone[idx] = 0u;
  if (idx < BB * 16) { g_fhd[idx] = 0u; g_sfd[idx] = 0u; }
  if (idx < BB * 4 * 8) { g_afl[idx] = 0ull; g_bfl[idx] = 0ull; }
}

__global__ __launch_bounds__(512, 1) void wavernn_main(
    const float* __restrict__ cond, const float* __restrict__ gib,
    const float* __restrict__ W_h,  const float* __restrict__ b_h,
    const float* __restrict__ W_ci, const float* __restrict__ b_ci,
    const float* __restrict__ W_fi, const float* __restrict__ b_fi,
    const float* __restrict__ W_bc, const float* __restrict__ b_bc,
    const float* __restrict__ W_bf, const float* __restrict__ b_bf,
    float* __restrict__ out) {
  extern __shared__ float smem[];
  const int wg = blockIdx.x, tid = threadIdx.x;

  if (wg < NC) {
    // ================= compute role: 8 waves, wave w = (type w>>2, chan wg*4+(w&3)) ======
    float* hlds = smem;                       // [16][900]
    int* smcv = (int*)(smem + 14400);         // [16]
    int* smfv = (int*)(smem + 14416);         // [16]
    const int wave = tid >> 6, lane = tid & 63;
    const int l32 = lane >> 1, b2 = lane & 1;
    const int tp = wave >> 2;                 // 0=coarse rows, 1=fine rows
    const int chan = (wg << 2) | (wave & 3);  // 0..447
    const int rb = tp ? (HF + chan) : chan;
    float4 w[3][7];
    float brow[3];
#pragma unroll
    for (int r = 0; r < 3; ++r) {
      const int row = r * SZ + rb;
      brow[r] = b_h[row];
#pragma unroll
      for (int m = 0; m < 7; ++m)
        w[r][m] = *(const float4*)&W_h[(size_t)row * SZ + 4 * l32 + 128 * m];
    }
    float wci0[3], wci1[3], bcie[3];
    if (tp == 0) {
#pragma unroll
      for (int g = 0; g < 3; ++g) {
        const int rr = g * HF + chan;
        wci0[g] = W_ci[2 * rr]; wci1[g] = W_ci[2 * rr + 1];
        bcie[g] = b_ci[rr] + gib[g * SZ + chan];
      }
    }
    float pc0 = 0.f, pc1 = 0.f, pc2 = 0.f;
    if (tp == 0 && lane < 16) {
      const size_t base = (((size_t)lane * TT) * 3) * SZ + chan;
      pc0 = cond[base]; pc1 = cond[base + SZ]; pc2 = cond[base + 2 * SZ];
    }
    float chreg = 0.f;
    const int r16 = tid & 15, c28 = tid >> 4;   // staging coords (c28<28 active)

    for (int t = 0; t < TT; ++t) {
      const int p = (t & 1) ^ 1;   // hidden_{t-1}
      const int q = t & 1;         // destinations for step t
      // ---- Phase A: compute barrier; stage coarse half; coarse-K matvec
      if (tid < NC) waitFlagA(&g_cdone[tid * 16], (uint32_t)t);
      __syncthreads();
      if (c28 < 28) {
        const float* src = g_hid + (size_t)p * BB * SZ + r16 * SZ + c28 * 16;
        f32x4 a0, a1, a2, a3;
        cload4x4(src, a0, a1, a2, a3);
        float* dst = hlds + r16 * 900 + c28 * 16;
        *(f32x4*)(dst) = a0; *(f32x4*)(dst + 4) = a1;
        *(f32x4*)(dst + 8) = a2; *(f32x4*)(dst + 12) = a3;
      }
      __syncthreads();
      float acc[3][8];
#pragma unroll
      for (int r = 0; r < 3; ++r)
#pragma unroll
        for (int i = 0; i < 8; ++i) acc[r][i] = 0.f;
#pragma unroll
      for (int i = 0; i < 8; ++i) {
        const int b = b2 + 2 * i;
        const float* hb = hlds + b * 900 + 4 * l32;
        const float4 h0 = *(const float4*)(hb);
        const float4 h1 = *(const float4*)(hb + 128);
        const float4 h2 = *(const float4*)(hb + 256);
#pragma unroll
        for (int r = 0; r < 3; ++r) {
          float s = acc[r][i];
          s = fmaf(w[r][0].x, h0.x, s); s = fmaf(w[r][0].y, h0.y, s);
          s = fmaf(w[r][0].z, h0.z, s); s = fmaf(w[r][0].w, h0.w, s);
          s = fmaf(w[r][1].x, h1.x, s); s = fmaf(w[r][1].y, h1.y, s);
          s = fmaf(w[r][1].z, h1.z, s); s = fmaf(w[r][1].w, h1.w, s);
          s = fmaf(w[r][2].x, h2.x, s); s = fmaf(w[r][2].y, h2.y, s);
          s = fmaf(w[r][2].z, h2.z, s); s = fmaf(w[r][2].w, h2.w, s);
          acc[r][i] = s;
        }
        if (l32 < 16) {
          const float4 h3 = *(const float4*)(hb + 384);
#pragma unroll
          for (int r = 0; r < 3; ++r) {
            float s = acc[r][i];
            s = fmaf(w[r][3].x, h3.x, s); s = fmaf(w[r][3].y, h3.y, s);
            s = fmaf(w[r][3].z, h3.z, s); s = fmaf(w[r][3].w, h3.w, s);
            acc[r][i] = s;
          }
        }
      }
      // ---- Phase B1: fh_{t-1} published by F0s (payload sc_{t-1}); stage fine half
      if (tid < BB) {
        const uint32_t v = waitFlagHi8(&g_fhd[tid * 16], (uint32_t)t);
        smcv[tid] = (int)(v & 255u);
      }
      __syncthreads();
      if (c28 < 28) {
        const float* src = g_hid + (size_t)p * BB * SZ + r16 * SZ + HF + c28 * 16;
        f32x4 a0, a1, a2, a3;
        cload4x4(src, a0, a1, a2, a3);
        float* dst = hlds + r16 * 900 + HF + c28 * 16;
        *(f32x4*)(dst) = a0; *(f32x4*)(dst + 4) = a1;
        *(f32x4*)(dst + 8) = a2; *(f32x4*)(dst + 12) = a3;
      }
      __syncthreads();
#pragma unroll
      for (int i = 0; i < 8; ++i) {
        const int b = b2 + 2 * i;
        const float* hb = hlds + b * 900 + 4 * l32;
        if (l32 >= 16) {
          const float4 h3 = *(const float4*)(hb + 384);
#pragma unroll
          for (int r = 0; r < 3; ++r) {
            float s = acc[r][i];
            s = fmaf(w[r][3].x, h3.x, s); s = fmaf(w[r][3].y, h3.y, s);
            s = fmaf(w[r][3].z, h3.z, s); s = fmaf(w[r][3].w, h3.w, s);
            acc[r][i] = s;
          }
        }
        const float4 h4 = *(const float4*)(hb + 512);
        const float4 h5 = *(const float4*)(hb + 640);
        const float4 h6 = *(const float4*)(hb + 768);
#pragma unroll
        for (int r = 0; r < 3; ++r) {
          float s = acc[r][i];
          s = fmaf(w[r][4].x, h4.x, s); s = fmaf(w[r][4].y, h4.y, s);
          s = fmaf(w[r][4].z, h4.z, s); s = fmaf(w[r][4].w, h4.w, s);
          s = fmaf(w[r][5].x, h5.x, s); s = fmaf(w[r][5].y, h5.y, s);
          s = fmaf(w[r][5].z, h5.z, s); s = fmaf(w[r][5].w, h5.w, s);
          s = fmaf(w[r][6].x, h6.x, s); s = fmaf(w[r][6].y, h6.y, s);
          s = fmaf(w[r][6].z, h6.z, s); s = fmaf(w[r][6].w, h6.w, s);
          acc[r][i] = s;
        }
      }
#pragma unroll
      for (int r = 0; r < 3; ++r)
#pragma unroll
        for (int i = 0; i < 8; ++i) {
          float v = acc[r][i];
          v += __shfl_xor(v, 2);
          v += __shfl_xor(v, 4);
          v += __shfl_xor(v, 8);
          v += __shfl_xor(v, 16);
          v += __shfl_xor(v, 32);
          acc[r][i] = v;
        }
      // ---- Phase B2: sf_{t-1}; gates + publish
      if (tid < BB) {
        const uint32_t v = waitFlagHi8(&g_sfd[tid * 16], (uint32_t)t);
        smfv[tid] = (int)(v & 255u);
      }
      __syncthreads();
      if (lane < 16) {
        const int bb = lane, i = lane >> 1;
        const float s0 = acc[0][i] + brow[0];
        const float s1 = acc[1][i] + brow[1];
        const float s2 = acc[2][i] + brow[2];
        if (tp == 0) {
          const float cvv = (float)smcv[bb] / 127.5f - 1.0f;
          const float fvv = (float)smfv[bb] / 127.5f - 1.0f;
          const float cp0 = fmaf(cvv, wci0[0], fmaf(fvv, wci1[0], bcie[0])) + pc0;
          const float cp1 = fmaf(cvv, wci0[1], fmaf(fvv, wci1[1], bcie[1])) + pc1;
          const float cp2 = fmaf(cvv, wci0[2], fmaf(fvv, wci1[2], bcie[2])) + pc2;
          const float rg = 1.f / (1.f + expf(-(cp0 + s0)));
          const float ug = 1.f / (1.f + expf(-(cp1 + s1)));
          const float eg = tanhf(fmaf(rg, s2, cp2));
          const float chn = ug * chreg + (1.f - ug) * eg;
          chreg = chn;
          cstore1d(&g_hid[(size_t)q * BB * SZ + bb * SZ + chan], chn);
        } else {
          f32x4 hv; hv.x = s0; hv.y = s1; hv.z = s2; hv.w = 0.f;
          cstore4d(&g_hpf4[((size_t)chan * 16 + bb) * 4], hv);
        }
      }
      __syncthreads();
      if (tid == 0) cstore1u_nw(&g_cdone[wg * 16], (uint32_t)(t + 1));
      if (tp == 0 && lane < 16 && t + 1 < TT) {
        const size_t base = (((size_t)lane * TT + (t + 1)) * 3) * SZ + chan;
        pc0 = cond[base]; pc1 = cond[base + SZ]; pc2 = cond[base + 2 * SZ];
      }
    }
  } else {
    // ================= sampler role: 8 WGs/batch = 4 coarse-slice + 4 fine-slice =========
    const int swg = wg - NC;            // 0..127
    const int b = swg >> 3;
    const int role = (swg >> 2) & 1;    // 0 = coarse, 1 = fine
    const int k = swg & 3;              // 64-bin slice
    float* wlds = smem;                 // [448][65] padded weight slice
    float* vlds = smem + 29120;         // [448]: C: staged ch_t; F: local fh
    float* plds = smem + 29568;         // [8][64] K-partials
    float* aS = smem + 30080;           // [4]
    int*   aI = (int*)(smem + 30084);   // [4]
    float* bS = smem + 30088;           // [4]
    int*   bI = (int*)(smem + 30092);   // [4]
    // fill LDS weight slice (coalesced global reads, pad-65 conflict-free LDS writes)
    {
      const float* Wm = role ? W_bf : W_bc;
      for (int i = tid; i < HF * 64; i += 512) {
        const int bn = i / HF, kk = i - bn * HF;
        wlds[kk * 65 + bn] = Wm[(size_t)(64 * k + bn) * HF + kk];
      }
    }
    const float* bias = role ? b_bf : b_bc;
    // fine-role per-thread gate params (channel = tid < 448)
    float wf0[3], wf1[3], wf2[3], bfe[3];
    float cp0 = 0.f, cp1 = 0.f, cp2 = 0.f;
    if (role == 1 && tid < HF) {
#pragma unroll
      for (int g = 0; g < 3; ++g) {
        const int rr = g * HF + tid;
        wf0[g] = W_fi[3 * rr]; wf1[g] = W_fi[3 * rr + 1]; wf2[g] = W_fi[3 * rr + 2];
        bfe[g] = b_fi[rr] + gib[g * SZ + HF + tid];
      }
      const size_t cbase = (((size_t)b * TT) * 3) * SZ + HF + tid;
      cp0 = cond[cbase]; cp1 = cond[cbase + SZ]; cp2 = cond[cbase + 2 * SZ];
      vlds[tid] = 0.f;   // fh_{-1} = 0
    }
    __syncthreads();
    float cvO = -1.f, fvO = -1.f;

    for (int t = 0; t < TT; ++t) {
      const int q = t & 1;
      // per-step keys + gumbel for own bins (before any wait — off critical path)
      const uint2 kf = tf2(0u, 1u, 0u, (uint32_t)t);
      float gub = 0.f;
      if (tid < 64) {
        const uint2 kk = role ? tf2(kf.x, kf.y, 0u, 1u) : tf2(kf.x, kf.y, 0u, 0u);
        const uint2 o = tf2(kk.x, kk.y, 0u, (uint32_t)(b * 256 + 64 * k + tid));
        gub = gumbel_bits(o.x ^ o.y);
      }
      if (role == 0) {
        // ---------------- coarse-slice WG ----------------
        if (tid < NC) waitFlag(&g_cdone[tid * 16], (uint32_t)(t + 1));
        __syncthreads();
        if (tid < 112) {
          const f32x4 v = cload1x4(g_hid + (size_t)q * BB * SZ + b * SZ + 4 * tid);
          *(f32x4*)&vlds[4 * tid] = v;
        }
        __syncthreads();
        logits64(wlds, vlds, plds, tid);
        __syncthreads();
        if (tid < 64) {
          const float p0 = plds[tid],       p1 = plds[64 + tid];
          const float p2 = plds[128 + tid], p3 = plds[192 + tid];
          const float p4 = plds[256 + tid], p5 = plds[320 + tid];
          const float p6 = plds[384 + tid], p7 = plds[448 + tid];
          const float sum = ((p0 + p1) + (p2 + p3)) + ((p4 + p5) + (p6 + p7));
          float s = (sum + bias[64 * k + tid]) + gub;
          int idx = 64 * k + tid;
#pragma unroll
          for (int m = 1; m < 64; m <<= 1) {
            const float so = __shfl_xor(s, m);
            const int io = __shfl_xor(idx, m);
            if (so > s || (so == s && io < idx)) { s = so; idx = io; }
          }
          if (tid == 0) {
            f32x2 v; v.x = s;
            v.y = __uint_as_float(((uint32_t)(t + 1) << 16) | ((uint32_t)idx << 8));
            cstore2u_nw(&g_afl[(b * 4 + k) * 8], v);
          }
        }
        // vlds keeps ch_t; at t=999 it holds ch_999 for the final-hidden write
      } else {
        // ---------------- fine-slice WG ----------------
        if (tid < NC) waitFlag(&g_cdone[tid * 16], (uint32_t)(t + 1));
        __syncthreads();
        f32x4 hp = {0.f, 0.f, 0.f, 0.f};
        if (tid < HF) hp = cload1x4(g_hpf4 + ((size_t)tid * 16 + b) * 4);
        if (tid >= 448 && tid < 452) {   // idle threads poll the 4 coarse candidates
          const unsigned long long u = waitFlag64(&g_afl[(b * 4 + (tid - 448)) * 8], (uint32_t)(t + 1));
          aS[tid - 448] = __uint_as_float((uint32_t)u);
          aI[tid - 448] = (int)((u >> 40) & 255u);
        }
        __syncthreads();
        float ms = aS[0]; int sc = aI[0];
#pragma unroll
        for (int m = 1; m < 4; ++m) {
          const float so = aS[m]; const int io = aI[m];
          if (so > ms || (so == ms && io < sc)) { ms = so; sc = io; }
        }
        const float cvNew = (float)sc / 127.5f - 1.0f;
        if (tid < HF) {   // all 448 fine gates, redundantly per F-WG (bit-identical)
          const float fp0 = fmaf(cvO, wf0[0], fmaf(fvO, wf1[0], fmaf(cvNew, wf2[0], bfe[0]))) + cp0;
          const float fp1 = fmaf(cvO, wf0[1], fmaf(fvO, wf1[1], fmaf(cvNew, wf2[1], bfe[1]))) + cp1;
          const float fp2 = fmaf(cvO, wf0[2], fmaf(fvO, wf1[2], fmaf(cvNew, wf2[2], bfe[2]))) + cp2;
          const float fhold = vlds[tid];
          const float rg = 1.f / (1.f + expf(-(fp0 + hp.x)));
          const float ug = 1.f / (1.f + expf(-(fp1 + hp.y)));
          const float eg = tanhf(fmaf(rg, hp.z, fp2));
          vlds[tid] = ug * fhold + (1.f - ug) * eg;
        }
        __syncthreads();
        if (k == 0) {
          if (tid < 112)
            cstore4d(&g_hid[(size_t)q * BB * SZ + b * SZ + HF + 4 * tid], *(f32x4*)&vlds[4 * tid]);
          __syncthreads();
          if (tid == 0) cstore1u_nw(&g_fhd[b * 16], ((uint32_t)(t + 1) << 8) | (uint32_t)sc);
        }
        logits64(wlds, vlds, plds, tid);
        __syncthreads();
        if (tid < 64) {
          const float p0 = plds[tid],       p1 = plds[64 + tid];
          const float p2 = plds[128 + tid], p3 = plds[192 + tid];
          const float p4 = plds[256 + tid], p5 = plds[320 + tid];
          const float p6 = plds[384 + tid], p7 = plds[448 + tid];
          const float sum = ((p0 + p1) + (p2 + p3)) + ((p4 + p5) + (p6 + p7));
          float s = (sum + bias[64 * k + tid]) + gub;
          int idx = 64 * k + tid;
#pragma unroll
          for (int m = 1; m < 64; m <<= 1) {
            const float so = __shfl_xor(s, m);
            const int io = __shfl_xor(idx, m);
            if (so > s || (so == s && io < idx)) { s = so; idx = io; }
          }
          if (tid == 0) {
            f32x2 v; v.x = s;
            v.y = __uint_as_float(((uint32_t)(t + 1) << 16) | ((uint32_t)idx << 8));
            cstore2u_nw(&g_bfl[(b * 4 + k) * 8], v);
          }
        }
        if (tid >= 448 && tid < 452) {
          const unsigned long long u = waitFlag64(&g_bfl[(b * 4 + (tid - 448)) * 8], (uint32_t)(t + 1));
          bS[tid - 448] = __uint_as_float((uint32_t)u);
          bI[tid - 448] = (int)((u >> 40) & 255u);
        }
        __syncthreads();
        float msf = bS[0]; int sf = bI[0];
#pragma unroll
        for (int m = 1; m < 4; ++m) {
          const float so = bS[m]; const int io = bI[m];
          if (so > msf || (so == msf && io < sf)) { msf = so; sf = io; }
        }
        if (k == 0 && tid == 0) {
          out[b * TT + t] = (float)sc;
          out[BB * TT + b * TT + t] = (float)sf;
          cstore1u_nw(&g_sfd[b * 16], ((uint32_t)(t + 1) << 8) | (uint32_t)sf);
        }
        cvO = cvNew; fvO = (float)sf / 127.5f - 1.0f;
        if (tid < HF && t + 1 < TT) {
          const size_t cbase = (((size_t)b * TT + (t + 1)) * 3) * SZ + HF + tid;
          cp0 = cond[cbase]; cp1 = cond[cbase + SZ]; cp2 = cond[cbase + 2 * SZ];
        }
      }
    }
    // final hidden: C0 writes ch_999 (vlds), F0 writes fh_999 (vlds)
    if (k == 0) {
      if (role == 0) {
        if (tid < HF) out[2 * BB * TT + (size_t)b * SZ + tid] = vlds[tid];
      } else {
        if (tid < HF) out[2 * BB * TT + (size_t)b * SZ + HF + tid] = vlds[tid];
      }
    }
  }
}

extern "C" void kernel_launch(void* const* d_in, const int* in_sizes, int n_in,
                              void* d_out, int out_size, void* d_ws, size_t ws_size,
                              hipStream_t stream) {
  (void)in_sizes; (void)n_in; (void)out_size; (void)d_ws; (void)ws_size;
  const float* cond = (const float*)d_in[0];
  const float* gib  = (const float*)d_in[1];
  const float* W_h  = (const float*)d_in[2];
  const float* b_h  = (const float*)d_in[3];
  const float* W_ci = (const float*)d_in[4];
  const float* b_ci = (const float*)d_in[5];
  const float* W_fi = (const float*)d_in[6];
  const float* b_fi = (const float*)d_in[7];
  const float* W_bc = (const float*)d_in[8];
  const float* b_bc = (const float*)d_in[9];
  const float* W_bf = (const float*)d_in[10];
  const float* b_bf = (const float*)d_in[11];
  float* out = (float*)d_out;
  static int attr_done = 0;
  (void)attr_done;
  hipFuncSetAttribute((const void*)wavernn_main,
                      hipFuncAttributeMaxDynamicSharedMemorySize, LDS_BYTES);
  wavernn_init<<<NC, 256, 0, stream>>>();
  wavernn_main<<<NWG, 512, LDS_BYTES, stream>>>(cond, gib, W_h, b_h, W_ci, b_ci,
                                                W_fi, b_fi, W_bc, b_bc, W_bf, b_bf, out);
}